// Round 4
// baseline (924.618 us; speedup 1.0000x reference)
//
#include <hip/hip_runtime.h>
#include <hip/hip_bf16.h>

#define N_GRAPHS 64
#define IN_FEATS 64
#define HIDDEN 32
#define OUT_DIM 2

#define NB 512        // buckets (node ranges); LDS arrays sized to this
#define NBSZ_MAX 256  // max nodes per bucket supported by LDS accumulators
#define PCH 6144      // edges per partition block (LDS stage = 48 KB)

// ---------------- dense linears (node-parallel) ----------------

// t1 = node_feats(f32 [N,64]) @ W1(f32 [64,32]) -> f32 [N,32]   (bias deferred)
__global__ void k_lin1(const float* __restrict__ nf,
                       const float* __restrict__ W,
                       float* __restrict__ out, int n) {
    __shared__ float w[IN_FEATS * HIDDEN];
    for (int i = threadIdx.x; i < IN_FEATS * HIDDEN; i += blockDim.x)
        w[i] = W[i];
    __syncthreads();
    int row = blockIdx.x * blockDim.x + threadIdx.x;
    if (row >= n) return;

    float a[IN_FEATS];
    const float4* r4 = reinterpret_cast<const float4*>(nf + (long long)row * IN_FEATS);
    #pragma unroll
    for (int v = 0; v < IN_FEATS / 4; v++) {
        float4 q = r4[v];
        a[v * 4 + 0] = q.x; a[v * 4 + 1] = q.y; a[v * 4 + 2] = q.z; a[v * 4 + 3] = q.w;
    }
    float acc[HIDDEN];
    #pragma unroll
    for (int f = 0; f < HIDDEN; f++) acc[f] = 0.f;
    for (int k = 0; k < IN_FEATS; k++) {
        float av = a[k];
        #pragma unroll
        for (int f = 0; f < HIDDEN; f++) acc[f] += av * w[k * HIDDEN + f];
    }
    float* o = out + (long long)row * HIDDEN;
    #pragma unroll
    for (int f = 0; f < HIDDEN; f++) o[f] = acc[f];
}

// t = (agg(f32 [N,32]) + b[32]) @ W(f32 [32,32]) -> f32 [N,32]
__global__ void k_lin2(const float* __restrict__ in,
                       const float* __restrict__ b,
                       const float* __restrict__ W,
                       float* __restrict__ out, int n) {
    __shared__ float w[HIDDEN * HIDDEN];
    __shared__ float bs[HIDDEN];
    for (int i = threadIdx.x; i < HIDDEN * HIDDEN; i += blockDim.x) w[i] = W[i];
    if (threadIdx.x < HIDDEN) bs[threadIdx.x] = b[threadIdx.x];
    __syncthreads();
    int row = blockIdx.x * blockDim.x + threadIdx.x;
    if (row >= n) return;

    float a[HIDDEN];
    const float4* r4 = reinterpret_cast<const float4*>(in + (long long)row * HIDDEN);
    #pragma unroll
    for (int v = 0; v < HIDDEN / 4; v++) {
        float4 q = r4[v];
        a[v * 4 + 0] = q.x; a[v * 4 + 1] = q.y; a[v * 4 + 2] = q.z; a[v * 4 + 3] = q.w;
    }
    #pragma unroll
    for (int k = 0; k < HIDDEN; k++) a[k] += bs[k];
    float acc[HIDDEN];
    #pragma unroll
    for (int f = 0; f < HIDDEN; f++) acc[f] = 0.f;
    for (int k = 0; k < HIDDEN; k++) {
        float av = a[k];
        #pragma unroll
        for (int f = 0; f < HIDDEN; f++) acc[f] += av * w[k * HIDDEN + f];
    }
    float* o = out + (long long)row * HIDDEN;
    #pragma unroll
    for (int f = 0; f < HIDDEN; f++) o[f] = acc[f];
}

// t3 = (agg2 + b2) @ W3(f32 [32,2]) -> f32 [N,2]
__global__ void k_lin3(const float* __restrict__ in,
                       const float* __restrict__ b,
                       const float* __restrict__ W,
                       float* __restrict__ out, int n) {
    __shared__ float w[HIDDEN * OUT_DIM];
    __shared__ float bs[HIDDEN];
    for (int i = threadIdx.x; i < HIDDEN * OUT_DIM; i += blockDim.x) w[i] = W[i];
    if (threadIdx.x < HIDDEN) bs[threadIdx.x] = b[threadIdx.x];
    __syncthreads();
    int row = blockIdx.x * blockDim.x + threadIdx.x;
    if (row >= n) return;

    const float4* r4 = reinterpret_cast<const float4*>(in + (long long)row * HIDDEN);
    float acc0 = 0.f, acc1 = 0.f;
    #pragma unroll
    for (int v = 0; v < HIDDEN / 4; v++) {
        float4 q = r4[v];
        float av;
        av = q.x + bs[v * 4 + 0]; acc0 += av * w[(v * 4 + 0) * 2]; acc1 += av * w[(v * 4 + 0) * 2 + 1];
        av = q.y + bs[v * 4 + 1]; acc0 += av * w[(v * 4 + 1) * 2]; acc1 += av * w[(v * 4 + 1) * 2 + 1];
        av = q.z + bs[v * 4 + 2]; acc0 += av * w[(v * 4 + 2) * 2]; acc1 += av * w[(v * 4 + 2) * 2 + 1];
        av = q.w + bs[v * 4 + 3]; acc0 += av * w[(v * 4 + 3) * 2]; acc1 += av * w[(v * 4 + 3) * 2 + 1];
    }
    float2* o = reinterpret_cast<float2*>(out + (long long)row * OUT_DIM);
    *o = make_float2(acc0, acc1);
}

// ---------------- edge bucketing (coarse, by dst range) ----------------

// global per-bucket edge counts
__global__ __launch_bounds__(256) void k_hist(const int* __restrict__ dst,
                                              int* __restrict__ gcount,
                                              int E, int nb_sz) {
    __shared__ int lc[NB];
    for (int k = threadIdx.x; k < NB; k += 256) lc[k] = 0;
    __syncthreads();
    int stride = gridDim.x * 256;
    for (int i = blockIdx.x * 256 + threadIdx.x; i < E; i += stride)
        atomicAdd(&lc[dst[i] / nb_sz], 1);
    __syncthreads();
    for (int k = threadIdx.x; k < NB; k += 256)
        if (lc[k]) atomicAdd(&gcount[k], lc[k]);
}

// exclusive scan of gcount[NB] -> gbase[NB+1], init gcur; single block of 256
__global__ __launch_bounds__(256) void k_scan512(const int* __restrict__ gcount,
                                                 int* __restrict__ gbase,
                                                 int* __restrict__ gcur, int E) {
    __shared__ int sA[NB], sB[NB];
    int tid = threadIdx.x;
    int c0 = gcount[tid], c1 = gcount[tid + 256];
    sA[tid] = c0; sA[tid + 256] = c1;
    __syncthreads();
    int* a = sA; int* bb = sB;
    for (int off = 1; off < NB; off <<= 1) {
        for (int k = tid; k < NB; k += 256) {
            int v = a[k];
            if (k >= off) v += a[k - off];
            bb[k] = v;
        }
        __syncthreads();
        int* t_ = a; a = bb; bb = t_;
    }
    int e0 = a[tid] - c0, e1 = a[tid + 256] - c1;
    gbase[tid] = e0;       gbase[tid + 256] = e1;
    gcur[tid] = e0;        gcur[tid + 256] = e1;
    if (tid == 0) gbase[NB] = E;
}

// partition edges into bucket segments; LDS-staged so global writes are runs
__global__ __launch_bounds__(256) void k_partition(const int* __restrict__ src,
                                                   const int* __restrict__ dst,
                                                   int* __restrict__ gcur,
                                                   uint2* __restrict__ pairs,
                                                   int E, int nb_sz) {
    __shared__ uint2 stage[PCH];
    __shared__ int sA[NB], sB[NB], ofs[NB + 1], cur[NB], rbase[NB];
    int tid = threadIdx.x;
    int e0 = blockIdx.x * PCH;
    int m = E - e0; if (m > PCH) m = PCH;

    for (int k = tid; k < NB; k += 256) sA[k] = 0;
    __syncthreads();
    // local histogram
    for (int i = tid; i < m; i += 256)
        atomicAdd(&sA[dst[e0 + i] / nb_sz], 1);
    __syncthreads();
    int c0 = sA[tid], c1 = sA[tid + 256];   // snapshot counts
    // inclusive scan (ping-pong)
    int* a = sA; int* bb = sB;
    for (int off = 1; off < NB; off <<= 1) {
        for (int k = tid; k < NB; k += 256) {
            int v = a[k];
            if (k >= off) v += a[k - off];
            bb[k] = v;
        }
        __syncthreads();
        int* t_ = a; a = bb; bb = t_;
    }
    int x0 = a[tid] - c0, x1 = a[tid + 256] - c1;  // exclusive
    ofs[tid] = x0;       ofs[tid + 256] = x1;
    cur[tid] = x0;       cur[tid + 256] = x1;
    if (tid == 0) ofs[NB] = m;
    __syncthreads();
    // scatter into LDS stage, bucket-grouped
    for (int i = tid; i < m; i += 256) {
        int d = dst[e0 + i];
        int s = src[e0 + i];
        int b = d / nb_sz;
        int p = atomicAdd(&cur[b], 1);
        stage[p] = make_uint2((unsigned)s, (unsigned)d);
    }
    __syncthreads();
    // reserve global runs (one atomic per non-empty (block,bucket))
    for (int k = tid; k < NB; k += 256) {
        int cnt = ofs[k + 1] - ofs[k];
        rbase[k] = cnt > 0 ? atomicAdd(&gcur[k], cnt) : 0;
    }
    __syncthreads();
    // write out runs (contiguous per bucket); bucket via binary search in ofs
    for (int i = tid; i < m; i += 256) {
        int lo = 0, hi = NB;
        while (hi - lo > 1) {
            int mid = (lo + hi) >> 1;
            if (ofs[mid] <= i) lo = mid; else hi = mid;
        }
        pairs[rbase[lo] + (i - ofs[lo])] = stage[i];
    }
}

// ---------------- bucket-parallel atomic-free-in-global gathers ----------------

// one block per (bucket, feature-half): agg[node][h*16+f] = sum t[src][h*16+f]
__global__ __launch_bounds__(256) void k_gather_b32(const float* __restrict__ t,
                                                    const uint2* __restrict__ pairs,
                                                    const int* __restrict__ gbase,
                                                    float* __restrict__ agg,
                                                    int N, int nb_sz) {
    int b = blockIdx.x >> 1;
    int h = blockIdx.x & 1;
    int n0 = b * nb_sz;
    if (n0 >= N) return;
    int n1 = n0 + nb_sz; if (n1 > N) n1 = N;
    int nn = n1 - n0;

    __shared__ float accum[NBSZ_MAX * 16];
    for (int k = threadIdx.x; k < nn * 16; k += 256) accum[k] = 0.f;
    __syncthreads();

    int s = gbase[b], e = gbase[b + 1];
    int g = threadIdx.x >> 4;       // 16 groups of 16 lanes
    int f = threadIdx.x & 15;
    int fo = h * 16 + f;

    int j = s + g;
    for (; j + 48 < e; j += 64) {
        uint2 p0 = pairs[j];
        uint2 p1 = pairs[j + 16];
        uint2 p2 = pairs[j + 32];
        uint2 p3 = pairs[j + 48];
        float v0 = t[p0.x * 32 + fo];
        float v1 = t[p1.x * 32 + fo];
        float v2 = t[p2.x * 32 + fo];
        float v3 = t[p3.x * 32 + fo];
        atomicAdd(&accum[(p0.y - (unsigned)n0) * 16 + f], v0);
        atomicAdd(&accum[(p1.y - (unsigned)n0) * 16 + f], v1);
        atomicAdd(&accum[(p2.y - (unsigned)n0) * 16 + f], v2);
        atomicAdd(&accum[(p3.y - (unsigned)n0) * 16 + f], v3);
    }
    for (; j < e; j += 16) {
        uint2 p = pairs[j];
        atomicAdd(&accum[(p.y - (unsigned)n0) * 16 + f], t[p.x * 32 + fo]);
    }
    __syncthreads();
    for (int k = threadIdx.x; k < nn * 16; k += 256) {
        int i = k >> 4, ff = k & 15;
        agg[(long long)(n0 + i) * 32 + h * 16 + ff] = accum[k];
    }
}

// layer-3 gather (2 feats) + bias, straight into d_out
__global__ __launch_bounds__(256) void k_gather2b(const float* __restrict__ t3,
                                                  const uint2* __restrict__ pairs,
                                                  const int* __restrict__ gbase,
                                                  const float* __restrict__ b3,
                                                  float* __restrict__ out,
                                                  int N, int nb_sz) {
    int b = blockIdx.x;
    int n0 = b * nb_sz;
    if (n0 >= N) return;
    int n1 = n0 + nb_sz; if (n1 > N) n1 = N;
    int nn = n1 - n0;

    __shared__ float acc2[NBSZ_MAX * 2];
    for (int k = threadIdx.x; k < nn * 2; k += 256) acc2[k] = 0.f;
    __syncthreads();

    int s = gbase[b], e = gbase[b + 1];
    int g = threadIdx.x >> 1;   // 128 groups of 2 lanes
    int f = threadIdx.x & 1;

    int j = s + g;
    for (; j + 128 < e; j += 256) {
        uint2 p0 = pairs[j];
        uint2 p1 = pairs[j + 128];
        float v0 = t3[p0.x * 2 + f];
        float v1 = t3[p1.x * 2 + f];
        atomicAdd(&acc2[(p0.y - (unsigned)n0) * 2 + f], v0);
        atomicAdd(&acc2[(p1.y - (unsigned)n0) * 2 + f], v1);
    }
    for (; j < e; j += 128) {
        uint2 p = pairs[j];
        atomicAdd(&acc2[(p.y - (unsigned)n0) * 2 + f], t3[p.x * 2 + f]);
    }
    __syncthreads();
    float bias0 = b3[0], bias1 = b3[1];
    for (int k = threadIdx.x; k < nn * 2; k += 256)
        out[(long long)n0 * 2 + k] = acc2[k] + ((k & 1) ? bias1 : bias0);
}

// ---------------- graph embedding + prediction ----------------

__global__ void k_bounds(const int* __restrict__ gids, int n, int* __restrict__ start) {
    int g = threadIdx.x;
    if (g > N_GRAPHS) return;
    int lo = 0, hi = n;
    while (lo < hi) {
        int mid = (lo + hi) >> 1;
        if (gids[mid] < g) lo = mid + 1; else hi = mid;
    }
    start[g] = lo;
}

__global__ void k_gsum(const float* __restrict__ nf,
                       const int* __restrict__ start,
                       float* __restrict__ ge) {
    int g = blockIdx.x;
    int s = start[g], e = start[g + 1];
    int f = threadIdx.x & 63;
    int sub = threadIdx.x >> 6;  // 0..3
    float acc = 0.f;
    for (int i = s + sub; i < e; i += 4)
        acc += nf[(long long)i * IN_FEATS + f];
    __shared__ float red[256];
    red[threadIdx.x] = acc;
    __syncthreads();
    if (threadIdx.x < 64) {
        float v = red[threadIdx.x] + red[threadIdx.x + 64] +
                  red[threadIdx.x + 128] + red[threadIdx.x + 192];
        float cnt = (float)(e - s);
        ge[g * IN_FEATS + threadIdx.x] = v / fmaxf(cnt, 1.0f);
    }
}

__global__ void k_pred(const float* __restrict__ ge,
                       const float* __restrict__ Wl,
                       const float* __restrict__ bl,
                       float* __restrict__ out) {
    int g = threadIdx.x;
    if (g >= N_GRAPHS) return;
    float acc = bl[0];
    for (int k = 0; k < IN_FEATS; k++)
        acc += ge[g * IN_FEATS + k] * Wl[k];
    out[g] = 1.f / (1.f + expf(-acc));
}

extern "C" void kernel_launch(void* const* d_in, const int* in_sizes, int n_in,
                              void* d_out, int out_size, void* d_ws, size_t ws_size,
                              hipStream_t stream) {
    const float* nf = (const float*)d_in[0];   // node_feats f32 [N,64]
    const float* W1 = (const float*)d_in[2];   // [64,32]
    const float* b1 = (const float*)d_in[3];   // [32]
    const float* W2 = (const float*)d_in[4];   // [32,32]
    const float* b2 = (const float*)d_in[5];   // [32]
    const float* W3 = (const float*)d_in[6];   // [32,2]
    const float* b3 = (const float*)d_in[7];   // [2]
    const float* Wl = (const float*)d_in[8];   // [64,1]
    const float* bl = (const float*)d_in[9];   // [1]
    const int* src  = (const int*)d_in[10];
    const int* dst  = (const int*)d_in[11];
    const int* gids = (const int*)d_in[12];

    const int N = in_sizes[0] / IN_FEATS;     // 100000
    const int E = in_sizes[10];               // 1600000
    const int nb_sz = (N + NB - 1) / NB;      // 196

    float* out = (float*)d_out;

    // workspace: bufA 12.8MB | bufB 12.8MB | pairs 12.8MB | small ints
    float* bufA  = (float*)d_ws;                 // t   [N,32] (t3 [N,2] in layer 3)
    float* bufB  = bufA + (size_t)N * HIDDEN;    // agg [N,32]
    uint2* pairs = (uint2*)(bufB + (size_t)N * HIDDEN); // [E] (src,dst)
    int* gcount  = (int*)(pairs + E);            // [NB]
    int* gbase   = gcount + NB;                  // [NB+1]
    int* gcur    = gbase + NB + 1;               // [NB]
    float* ge    = (float*)(gcur + NB);          // [64,64]
    int* gstart  = (int*)(ge + N_GRAPHS * IN_FEATS); // [65]

    const int TB = 256;
    int nodeBlocks = (N + TB - 1) / TB;
    int partBlocks = (E + PCH - 1) / PCH;

    // ---- bucket build (once, reused for all 3 layers) ----
    hipMemsetAsync(gcount, 0, NB * sizeof(int), stream);
    k_hist<<<256, TB, 0, stream>>>(dst, gcount, E, nb_sz);
    k_scan512<<<1, TB, 0, stream>>>(gcount, gbase, gcur, E);
    k_partition<<<partBlocks, TB, 0, stream>>>(src, dst, gcur, pairs, E, nb_sz);

    // ---- layer 1 ----
    k_lin1<<<nodeBlocks, TB, 0, stream>>>(nf, W1, bufA, N);
    k_gather_b32<<<NB * 2, TB, 0, stream>>>(bufA, pairs, gbase, bufB, N, nb_sz);

    // ---- layer 2 ----
    k_lin2<<<nodeBlocks, TB, 0, stream>>>(bufB, b1, W2, bufA, N);
    k_gather_b32<<<NB * 2, TB, 0, stream>>>(bufA, pairs, gbase, bufB, N, nb_sz);

    // ---- layer 3 ----
    k_lin3<<<nodeBlocks, TB, 0, stream>>>(bufB, b2, W3, bufA, N);
    k_gather2b<<<NB, TB, 0, stream>>>(bufA, pairs, gbase, b3, out + N_GRAPHS, N, nb_sz);

    // ---- graph embedding + prediction ----
    k_bounds<<<1, 128, 0, stream>>>(gids, N, gstart);
    k_gsum<<<N_GRAPHS, 256, 0, stream>>>(nf, gstart, ge);
    k_pred<<<1, 64, 0, stream>>>(ge, Wl, bl, out);
}

// Round 5
// 479.998 us; speedup vs baseline: 1.9263x; 1.9263x over previous
//
#include <hip/hip_runtime.h>
#include <hip/hip_bf16.h>

#define N_GRAPHS 64
#define IN_FEATS 64
#define HIDDEN 32
#define OUT_DIM 2

#define NB 512        // dst-range buckets
#define PCH 6144      // edges per partition block (LDS stage = 48 KB)

__device__ __forceinline__ float bf2f(unsigned short u) {
    unsigned int x = ((unsigned int)u) << 16;
    float f;
    __builtin_memcpy(&f, &x, 4);
    return f;
}

__device__ __forceinline__ unsigned short f2bf(float f) {
    __hip_bfloat16 h = __float2bfloat16(f);   // RNE
    unsigned short u;
    __builtin_memcpy(&u, &h, 2);
    return u;
}

// ---------------- dense linears (node-parallel) ----------------

// t1 = node_feats(f32 [N,64]) @ W1(f32 [64,32]) -> bf16 [N,32]   (bias deferred)
__global__ void k_lin1(const float* __restrict__ nf,
                       const float* __restrict__ W,
                       unsigned short* __restrict__ out, int n) {
    __shared__ float w[IN_FEATS * HIDDEN];
    for (int i = threadIdx.x; i < IN_FEATS * HIDDEN; i += blockDim.x)
        w[i] = W[i];
    __syncthreads();
    int row = blockIdx.x * blockDim.x + threadIdx.x;
    if (row >= n) return;

    float a[IN_FEATS];
    const float4* r4 = reinterpret_cast<const float4*>(nf + (long long)row * IN_FEATS);
    #pragma unroll
    for (int v = 0; v < IN_FEATS / 4; v++) {
        float4 q = r4[v];
        a[v * 4 + 0] = q.x; a[v * 4 + 1] = q.y; a[v * 4 + 2] = q.z; a[v * 4 + 3] = q.w;
    }
    float acc[HIDDEN];
    #pragma unroll
    for (int f = 0; f < HIDDEN; f++) acc[f] = 0.f;
    for (int k = 0; k < IN_FEATS; k++) {
        float av = a[k];
        #pragma unroll
        for (int f = 0; f < HIDDEN; f++) acc[f] += av * w[k * HIDDEN + f];
    }
    unsigned int packed[HIDDEN / 2];
    #pragma unroll
    for (int f = 0; f < HIDDEN / 2; f++)
        packed[f] = (unsigned int)f2bf(acc[2 * f]) | ((unsigned int)f2bf(acc[2 * f + 1]) << 16);
    uint4* o = reinterpret_cast<uint4*>(out + (long long)row * HIDDEN);
    #pragma unroll
    for (int v = 0; v < HIDDEN / 8; v++)
        o[v] = make_uint4(packed[v * 4], packed[v * 4 + 1], packed[v * 4 + 2], packed[v * 4 + 3]);
}

// t2 = (agg(f32 [N,32]) + b[32]) @ W(f32 [32,32]) -> bf16 [N,32]
__global__ void k_lin2(const float* __restrict__ in,
                       const float* __restrict__ b,
                       const float* __restrict__ W,
                       unsigned short* __restrict__ out, int n) {
    __shared__ float w[HIDDEN * HIDDEN];
    __shared__ float bs[HIDDEN];
    for (int i = threadIdx.x; i < HIDDEN * HIDDEN; i += blockDim.x) w[i] = W[i];
    if (threadIdx.x < HIDDEN) bs[threadIdx.x] = b[threadIdx.x];
    __syncthreads();
    int row = blockIdx.x * blockDim.x + threadIdx.x;
    if (row >= n) return;

    float a[HIDDEN];
    const float4* r4 = reinterpret_cast<const float4*>(in + (long long)row * HIDDEN);
    #pragma unroll
    for (int v = 0; v < HIDDEN / 4; v++) {
        float4 q = r4[v];
        a[v * 4 + 0] = q.x; a[v * 4 + 1] = q.y; a[v * 4 + 2] = q.z; a[v * 4 + 3] = q.w;
    }
    #pragma unroll
    for (int k = 0; k < HIDDEN; k++) a[k] += bs[k];
    float acc[HIDDEN];
    #pragma unroll
    for (int f = 0; f < HIDDEN; f++) acc[f] = 0.f;
    for (int k = 0; k < HIDDEN; k++) {
        float av = a[k];
        #pragma unroll
        for (int f = 0; f < HIDDEN; f++) acc[f] += av * w[k * HIDDEN + f];
    }
    unsigned int packed[HIDDEN / 2];
    #pragma unroll
    for (int f = 0; f < HIDDEN / 2; f++)
        packed[f] = (unsigned int)f2bf(acc[2 * f]) | ((unsigned int)f2bf(acc[2 * f + 1]) << 16);
    uint4* o = reinterpret_cast<uint4*>(out + (long long)row * HIDDEN);
    #pragma unroll
    for (int v = 0; v < HIDDEN / 8; v++)
        o[v] = make_uint4(packed[v * 4], packed[v * 4 + 1], packed[v * 4 + 2], packed[v * 4 + 3]);
}

// t3 = (agg2 + b2) @ W3(f32 [32,2]) -> f32 [N,2]
__global__ void k_lin3(const float* __restrict__ in,
                       const float* __restrict__ b,
                       const float* __restrict__ W,
                       float* __restrict__ out, int n) {
    __shared__ float w[HIDDEN * OUT_DIM];
    __shared__ float bs[HIDDEN];
    for (int i = threadIdx.x; i < HIDDEN * OUT_DIM; i += blockDim.x) w[i] = W[i];
    if (threadIdx.x < HIDDEN) bs[threadIdx.x] = b[threadIdx.x];
    __syncthreads();
    int row = blockIdx.x * blockDim.x + threadIdx.x;
    if (row >= n) return;

    const float4* r4 = reinterpret_cast<const float4*>(in + (long long)row * HIDDEN);
    float acc0 = 0.f, acc1 = 0.f;
    #pragma unroll
    for (int v = 0; v < HIDDEN / 4; v++) {
        float4 q = r4[v];
        float av;
        av = q.x + bs[v * 4 + 0]; acc0 += av * w[(v * 4 + 0) * 2]; acc1 += av * w[(v * 4 + 0) * 2 + 1];
        av = q.y + bs[v * 4 + 1]; acc0 += av * w[(v * 4 + 1) * 2]; acc1 += av * w[(v * 4 + 1) * 2 + 1];
        av = q.z + bs[v * 4 + 2]; acc0 += av * w[(v * 4 + 2) * 2]; acc1 += av * w[(v * 4 + 2) * 2 + 1];
        av = q.w + bs[v * 4 + 3]; acc0 += av * w[(v * 4 + 3) * 2]; acc1 += av * w[(v * 4 + 3) * 2 + 1];
    }
    float2* o = reinterpret_cast<float2*>(out + (long long)row * OUT_DIM);
    *o = make_float2(acc0, acc1);
}

// ---------------- CSR build: bucket partition + local counting sort ----------------

__global__ __launch_bounds__(256) void k_hist(const int* __restrict__ dst,
                                              int* __restrict__ gcount,
                                              int E, int nb_sz) {
    __shared__ int lc[NB];
    for (int k = threadIdx.x; k < NB; k += 256) lc[k] = 0;
    __syncthreads();
    int stride = gridDim.x * 256;
    for (int i = blockIdx.x * 256 + threadIdx.x; i < E; i += stride)
        atomicAdd(&lc[dst[i] / nb_sz], 1);
    __syncthreads();
    for (int k = threadIdx.x; k < NB; k += 256)
        if (lc[k]) atomicAdd(&gcount[k], lc[k]);
}

__global__ __launch_bounds__(256) void k_scan512(const int* __restrict__ gcount,
                                                 int* __restrict__ gbase,
                                                 int* __restrict__ gcur, int E) {
    __shared__ int sA[NB], sB[NB];
    int tid = threadIdx.x;
    int c0 = gcount[tid], c1 = gcount[tid + 256];
    sA[tid] = c0; sA[tid + 256] = c1;
    __syncthreads();
    int* a = sA; int* bb = sB;
    for (int off = 1; off < NB; off <<= 1) {
        for (int k = tid; k < NB; k += 256) {
            int v = a[k];
            if (k >= off) v += a[k - off];
            bb[k] = v;
        }
        __syncthreads();
        int* t_ = a; a = bb; bb = t_;
    }
    int e0 = a[tid] - c0, e1 = a[tid + 256] - c1;
    gbase[tid] = e0;       gbase[tid + 256] = e1;
    gcur[tid] = e0;        gcur[tid + 256] = e1;
    if (tid == 0) gbase[NB] = E;
}

__global__ __launch_bounds__(256) void k_partition(const int* __restrict__ src,
                                                   const int* __restrict__ dst,
                                                   int* __restrict__ gcur,
                                                   uint2* __restrict__ pairs,
                                                   int E, int nb_sz) {
    __shared__ uint2 stage[PCH];
    __shared__ int sA[NB], sB[NB], ofs[NB + 1], cur[NB], rbase[NB];
    int tid = threadIdx.x;
    int e0 = blockIdx.x * PCH;
    int m = E - e0; if (m > PCH) m = PCH;

    for (int k = tid; k < NB; k += 256) sA[k] = 0;
    __syncthreads();
    for (int i = tid; i < m; i += 256)
        atomicAdd(&sA[dst[e0 + i] / nb_sz], 1);
    __syncthreads();
    int c0 = sA[tid], c1 = sA[tid + 256];
    int* a = sA; int* bb = sB;
    for (int off = 1; off < NB; off <<= 1) {
        for (int k = tid; k < NB; k += 256) {
            int v = a[k];
            if (k >= off) v += a[k - off];
            bb[k] = v;
        }
        __syncthreads();
        int* t_ = a; a = bb; bb = t_;
    }
    int x0 = a[tid] - c0, x1 = a[tid + 256] - c1;
    ofs[tid] = x0;       ofs[tid + 256] = x1;
    cur[tid] = x0;       cur[tid + 256] = x1;
    if (tid == 0) ofs[NB] = m;
    __syncthreads();
    for (int i = tid; i < m; i += 256) {
        int d = dst[e0 + i];
        int s = src[e0 + i];
        int b = d / nb_sz;
        int p = atomicAdd(&cur[b], 1);
        stage[p] = make_uint2((unsigned)s, (unsigned)d);
    }
    __syncthreads();
    for (int k = tid; k < NB; k += 256) {
        int cnt = ofs[k + 1] - ofs[k];
        rbase[k] = cnt > 0 ? atomicAdd(&gcur[k], cnt) : 0;
    }
    __syncthreads();
    for (int i = tid; i < m; i += 256) {
        int lo = 0, hi = NB;
        while (hi - lo > 1) {
            int mid = (lo + hi) >> 1;
            if (ofs[mid] <= i) lo = mid; else hi = mid;
        }
        pairs[rbase[lo] + (i - ofs[lo])] = stage[i];
    }
}

// per-bucket counting sort -> csr (src only) + ptr (per-node END offsets)
// Each block writes only csr[gbase[b]..gbase[b+1]) — private region, L2-friendly.
__global__ __launch_bounds__(256) void k_csr_local(const uint2* __restrict__ pairs,
                                                   const int* __restrict__ gbase,
                                                   int* __restrict__ csr,
                                                   int* __restrict__ ptr,
                                                   int N, int nb_sz) {
    int b = blockIdx.x;
    int n0 = b * nb_sz;
    if (n0 >= N) return;
    int n1 = n0 + nb_sz; if (n1 > N) n1 = N;
    int nn = n1 - n0;

    __shared__ int cnt[256], scn[256], cur[256];
    int tid = threadIdx.x;
    cnt[tid] = 0;
    __syncthreads();
    int s = gbase[b], e = gbase[b + 1];
    for (int i = s + tid; i < e; i += 256)
        atomicAdd(&cnt[pairs[i].y - (unsigned)n0], 1);
    __syncthreads();
    int c = cnt[tid];
    scn[tid] = c;
    __syncthreads();
    for (int off = 1; off < 256; off <<= 1) {
        int mine = scn[tid];
        int add = (tid >= off) ? scn[tid - off] : 0;
        __syncthreads();
        scn[tid] = mine + add;
        __syncthreads();
    }
    cur[tid] = scn[tid] - c;                 // exclusive prefix
    if (tid < nn) ptr[n0 + tid] = s + scn[tid];   // end offset
    __syncthreads();
    for (int i = s + tid; i < e; i += 256) {
        uint2 p = pairs[i];
        int pos = atomicAdd(&cur[p.y - (unsigned)n0], 1);
        csr[s + pos] = (int)p.x;
    }
}

// ---------------- atomic-free per-node gathers ----------------

// agg[node][f] = sum over in-edges of bf16 t[src][f]; 32 lanes per node, f32 accumulate
__global__ __launch_bounds__(256) void k_gather32(const unsigned short* __restrict__ t,
                                                  const int* __restrict__ csr,
                                                  const int* __restrict__ ptr,
                                                  float* __restrict__ agg, int n) {
    int tid = blockIdx.x * blockDim.x + threadIdx.x;
    int node = tid >> 5;
    int f = tid & 31;
    if (node >= n) return;
    int start = node ? ptr[node - 1] : 0;
    int end = ptr[node];
    float acc = 0.f;
    int j = start;
    for (; j + 3 < end; j += 4) {
        int s0 = csr[j], s1 = csr[j + 1], s2 = csr[j + 2], s3 = csr[j + 3];
        float v0 = bf2f(t[s0 * 32 + f]);
        float v1 = bf2f(t[s1 * 32 + f]);
        float v2 = bf2f(t[s2 * 32 + f]);
        float v3 = bf2f(t[s3 * 32 + f]);
        acc += v0; acc += v1; acc += v2; acc += v3;
    }
    for (; j < end; j++)
        acc += bf2f(t[csr[j] * 32 + f]);
    agg[(long long)node * 32 + f] = acc;
}

// layer-3 gather (2 f32 feats) + bias, straight into d_out
__global__ void k_gather2_out(const float* __restrict__ t3,
                              const int* __restrict__ csr,
                              const int* __restrict__ ptr,
                              const float* __restrict__ b3,
                              float* __restrict__ out, int n) {
    int node = blockIdx.x * blockDim.x + threadIdx.x;
    if (node >= n) return;
    int start = node ? ptr[node - 1] : 0;
    int end = ptr[node];
    float a0 = 0.f, a1 = 0.f;
    int j = start;
    for (; j + 1 < end; j += 2) {
        int s0 = csr[j], s1 = csr[j + 1];
        float2 v0 = *reinterpret_cast<const float2*>(t3 + (long long)s0 * 2);
        float2 v1 = *reinterpret_cast<const float2*>(t3 + (long long)s1 * 2);
        a0 += v0.x + v1.x;
        a1 += v0.y + v1.y;
    }
    if (j < end) {
        float2 v = *reinterpret_cast<const float2*>(t3 + (long long)csr[j] * 2);
        a0 += v.x; a1 += v.y;
    }
    float2* o = reinterpret_cast<float2*>(out + (long long)node * 2);
    *o = make_float2(a0 + b3[0], a1 + b3[1]);
}

// ---------------- graph embedding + prediction ----------------

__global__ void k_bounds(const int* __restrict__ gids, int n, int* __restrict__ start) {
    int g = threadIdx.x;
    if (g > N_GRAPHS) return;
    int lo = 0, hi = n;
    while (lo < hi) {
        int mid = (lo + hi) >> 1;
        if (gids[mid] < g) lo = mid + 1; else hi = mid;
    }
    start[g] = lo;
}

__global__ void k_gsum(const float* __restrict__ nf,
                       const int* __restrict__ start,
                       float* __restrict__ ge) {
    int g = blockIdx.x;
    int s = start[g], e = start[g + 1];
    int f = threadIdx.x & 63;
    int sub = threadIdx.x >> 6;  // 0..3
    float acc = 0.f;
    for (int i = s + sub; i < e; i += 4)
        acc += nf[(long long)i * IN_FEATS + f];
    __shared__ float red[256];
    red[threadIdx.x] = acc;
    __syncthreads();
    if (threadIdx.x < 64) {
        float v = red[threadIdx.x] + red[threadIdx.x + 64] +
                  red[threadIdx.x + 128] + red[threadIdx.x + 192];
        float cnt = (float)(e - s);
        ge[g * IN_FEATS + threadIdx.x] = v / fmaxf(cnt, 1.0f);
    }
}

__global__ void k_pred(const float* __restrict__ ge,
                       const float* __restrict__ Wl,
                       const float* __restrict__ bl,
                       float* __restrict__ out) {
    int g = threadIdx.x;
    if (g >= N_GRAPHS) return;
    float acc = bl[0];
    for (int k = 0; k < IN_FEATS; k++)
        acc += ge[g * IN_FEATS + k] * Wl[k];
    out[g] = 1.f / (1.f + expf(-acc));
}

extern "C" void kernel_launch(void* const* d_in, const int* in_sizes, int n_in,
                              void* d_out, int out_size, void* d_ws, size_t ws_size,
                              hipStream_t stream) {
    const float* nf = (const float*)d_in[0];   // node_feats f32 [N,64]
    const float* W1 = (const float*)d_in[2];   // [64,32]
    const float* b1 = (const float*)d_in[3];   // [32]
    const float* W2 = (const float*)d_in[4];   // [32,32]
    const float* b2 = (const float*)d_in[5];   // [32]
    const float* W3 = (const float*)d_in[6];   // [32,2]
    const float* b3 = (const float*)d_in[7];   // [2]
    const float* Wl = (const float*)d_in[8];   // [64,1]
    const float* bl = (const float*)d_in[9];   // [1]
    const int* src  = (const int*)d_in[10];
    const int* dst  = (const int*)d_in[11];
    const int* gids = (const int*)d_in[12];

    const int N = in_sizes[0] / IN_FEATS;     // 100000
    const int E = in_sizes[10];               // 1600000
    const int nb_sz = (N + NB - 1) / NB;      // 196

    float* out = (float*)d_out;

    // workspace layout:
    // tb (bf16 t, 6.4MB) | agg f32 (12.8MB) | t3 f32 (0.8MB) | pairs (12.8MB) | csr (6.4MB) | ptr (0.4MB) | small
    unsigned short* tb = (unsigned short*)d_ws;            // [N,32] bf16
    float* agg   = (float*)(tb + (size_t)N * HIDDEN);      // [N,32] f32
    float* t3    = agg + (size_t)N * HIDDEN;               // [N,2]  f32
    uint2* pairs = (uint2*)(t3 + (size_t)N * OUT_DIM);     // [E]
    int* csr     = (int*)(pairs + E);                      // [E]
    int* ptr     = csr + E;                                // [N]
    int* gcount  = ptr + N;                                // [NB]
    int* gbase   = gcount + NB;                            // [NB+1]
    int* gcur    = gbase + NB + 1;                         // [NB]
    float* ge    = (float*)(gcur + NB);                    // [64,64]
    int* gstart  = (int*)(ge + N_GRAPHS * IN_FEATS);       // [65]

    const int TB = 256;
    int nodeBlocks = (N + TB - 1) / TB;
    int partBlocks = (E + PCH - 1) / PCH;
    int g32Blocks = (N * 32 + TB - 1) / TB;

    // ---- CSR build (once, reused for all 3 layers) ----
    hipMemsetAsync(gcount, 0, NB * sizeof(int), stream);
    k_hist<<<256, TB, 0, stream>>>(dst, gcount, E, nb_sz);
    k_scan512<<<1, TB, 0, stream>>>(gcount, gbase, gcur, E);
    k_partition<<<partBlocks, TB, 0, stream>>>(src, dst, gcur, pairs, E, nb_sz);
    k_csr_local<<<NB, TB, 0, stream>>>(pairs, gbase, csr, ptr, N, nb_sz);

    // ---- layer 1 ----
    k_lin1<<<nodeBlocks, TB, 0, stream>>>(nf, W1, tb, N);
    k_gather32<<<g32Blocks, TB, 0, stream>>>(tb, csr, ptr, agg, N);

    // ---- layer 2 ----
    k_lin2<<<nodeBlocks, TB, 0, stream>>>(agg, b1, W2, tb, N);
    k_gather32<<<g32Blocks, TB, 0, stream>>>(tb, csr, ptr, agg, N);

    // ---- layer 3 ----
    k_lin3<<<nodeBlocks, TB, 0, stream>>>(agg, b2, W3, t3, N);
    k_gather2_out<<<nodeBlocks, TB, 0, stream>>>(t3, csr, ptr, b3, out + N_GRAPHS, N);

    // ---- graph embedding + prediction ----
    k_bounds<<<1, 128, 0, stream>>>(gids, N, gstart);
    k_gsum<<<N_GRAPHS, 256, 0, stream>>>(nf, gstart, ge);
    k_pred<<<1, 64, 0, stream>>>(ge, Wl, bl, out);
}

// Round 6
// 406.096 us; speedup vs baseline: 2.2768x; 1.1820x over previous
//
#include <hip/hip_runtime.h>
#include <hip/hip_bf16.h>

#define N_GRAPHS 64
#define IN_FEATS 64
#define HIDDEN 32
#define OUT_DIM 2

#define NB 512        // dst-range buckets
#define PCH 8192      // edges per partition block (LDS stage = 32 KB packed)
#define GCH 256       // nodes per k_gsum2 chunk

__device__ __forceinline__ float bf2f(unsigned short u) {
    unsigned int x = ((unsigned int)u) << 16;
    float f;
    __builtin_memcpy(&f, &x, 4);
    return f;
}

__device__ __forceinline__ unsigned short f2bf(float f) {
    __hip_bfloat16 h = __float2bfloat16(f);   // RNE
    unsigned short u;
    __builtin_memcpy(&u, &h, 2);
    return u;
}

// ---------------- dense linears (node-parallel) ----------------

// t1 = node_feats(f32 [N,64]) @ W1(f32 [64,32]) -> bf16 [N,32]   (bias deferred)
__global__ void k_lin1(const float* __restrict__ nf,
                       const float* __restrict__ W,
                       unsigned short* __restrict__ out, int n) {
    __shared__ float w[IN_FEATS * HIDDEN];
    for (int i = threadIdx.x; i < IN_FEATS * HIDDEN; i += blockDim.x)
        w[i] = W[i];
    __syncthreads();
    int row = blockIdx.x * blockDim.x + threadIdx.x;
    if (row >= n) return;

    float a[IN_FEATS];
    const float4* r4 = reinterpret_cast<const float4*>(nf + (long long)row * IN_FEATS);
    #pragma unroll
    for (int v = 0; v < IN_FEATS / 4; v++) {
        float4 q = r4[v];
        a[v * 4 + 0] = q.x; a[v * 4 + 1] = q.y; a[v * 4 + 2] = q.z; a[v * 4 + 3] = q.w;
    }
    float acc[HIDDEN];
    #pragma unroll
    for (int f = 0; f < HIDDEN; f++) acc[f] = 0.f;
    for (int k = 0; k < IN_FEATS; k++) {
        float av = a[k];
        #pragma unroll
        for (int f = 0; f < HIDDEN; f++) acc[f] += av * w[k * HIDDEN + f];
    }
    unsigned int packed[HIDDEN / 2];
    #pragma unroll
    for (int f = 0; f < HIDDEN / 2; f++)
        packed[f] = (unsigned int)f2bf(acc[2 * f]) | ((unsigned int)f2bf(acc[2 * f + 1]) << 16);
    uint4* o = reinterpret_cast<uint4*>(out + (long long)row * HIDDEN);
    #pragma unroll
    for (int v = 0; v < HIDDEN / 8; v++)
        o[v] = make_uint4(packed[v * 4], packed[v * 4 + 1], packed[v * 4 + 2], packed[v * 4 + 3]);
}

// t2 = (agg(f32 [N,32]) + b[32]) @ W(f32 [32,32]) -> bf16 [N,32]
__global__ void k_lin2(const float* __restrict__ in,
                       const float* __restrict__ b,
                       const float* __restrict__ W,
                       unsigned short* __restrict__ out, int n) {
    __shared__ float w[HIDDEN * HIDDEN];
    __shared__ float bs[HIDDEN];
    for (int i = threadIdx.x; i < HIDDEN * HIDDEN; i += blockDim.x) w[i] = W[i];
    if (threadIdx.x < HIDDEN) bs[threadIdx.x] = b[threadIdx.x];
    __syncthreads();
    int row = blockIdx.x * blockDim.x + threadIdx.x;
    if (row >= n) return;

    float a[HIDDEN];
    const float4* r4 = reinterpret_cast<const float4*>(in + (long long)row * HIDDEN);
    #pragma unroll
    for (int v = 0; v < HIDDEN / 4; v++) {
        float4 q = r4[v];
        a[v * 4 + 0] = q.x; a[v * 4 + 1] = q.y; a[v * 4 + 2] = q.z; a[v * 4 + 3] = q.w;
    }
    #pragma unroll
    for (int k = 0; k < HIDDEN; k++) a[k] += bs[k];
    float acc[HIDDEN];
    #pragma unroll
    for (int f = 0; f < HIDDEN; f++) acc[f] = 0.f;
    for (int k = 0; k < HIDDEN; k++) {
        float av = a[k];
        #pragma unroll
        for (int f = 0; f < HIDDEN; f++) acc[f] += av * w[k * HIDDEN + f];
    }
    unsigned int packed[HIDDEN / 2];
    #pragma unroll
    for (int f = 0; f < HIDDEN / 2; f++)
        packed[f] = (unsigned int)f2bf(acc[2 * f]) | ((unsigned int)f2bf(acc[2 * f + 1]) << 16);
    uint4* o = reinterpret_cast<uint4*>(out + (long long)row * HIDDEN);
    #pragma unroll
    for (int v = 0; v < HIDDEN / 8; v++)
        o[v] = make_uint4(packed[v * 4], packed[v * 4 + 1], packed[v * 4 + 2], packed[v * 4 + 3]);
}

// t3 = (agg2 + b2) @ W3(f32 [32,2]) -> f32 [N,2]
__global__ void k_lin3(const float* __restrict__ in,
                       const float* __restrict__ b,
                       const float* __restrict__ W,
                       float* __restrict__ out, int n) {
    __shared__ float w[HIDDEN * OUT_DIM];
    __shared__ float bs[HIDDEN];
    for (int i = threadIdx.x; i < HIDDEN * OUT_DIM; i += blockDim.x) w[i] = W[i];
    if (threadIdx.x < HIDDEN) bs[threadIdx.x] = b[threadIdx.x];
    __syncthreads();
    int row = blockIdx.x * blockDim.x + threadIdx.x;
    if (row >= n) return;

    const float4* r4 = reinterpret_cast<const float4*>(in + (long long)row * HIDDEN);
    float acc0 = 0.f, acc1 = 0.f;
    #pragma unroll
    for (int v = 0; v < HIDDEN / 4; v++) {
        float4 q = r4[v];
        float av;
        av = q.x + bs[v * 4 + 0]; acc0 += av * w[(v * 4 + 0) * 2]; acc1 += av * w[(v * 4 + 0) * 2 + 1];
        av = q.y + bs[v * 4 + 1]; acc0 += av * w[(v * 4 + 1) * 2]; acc1 += av * w[(v * 4 + 1) * 2 + 1];
        av = q.z + bs[v * 4 + 2]; acc0 += av * w[(v * 4 + 2) * 2]; acc1 += av * w[(v * 4 + 2) * 2 + 1];
        av = q.w + bs[v * 4 + 3]; acc0 += av * w[(v * 4 + 3) * 2]; acc1 += av * w[(v * 4 + 3) * 2 + 1];
    }
    float2* o = reinterpret_cast<float2*>(out + (long long)row * OUT_DIM);
    *o = make_float2(acc0, acc1);
}

// ---------------- CSR build: bucket partition + local counting sort ----------------

__global__ __launch_bounds__(256) void k_hist(const int* __restrict__ dst,
                                              int* __restrict__ gcount,
                                              int E, int nb_sz) {
    __shared__ int lc[NB];
    for (int k = threadIdx.x; k < NB; k += 256) lc[k] = 0;
    __syncthreads();
    int stride = gridDim.x * 256;
    for (int i = blockIdx.x * 256 + threadIdx.x; i < E; i += stride)
        atomicAdd(&lc[dst[i] / nb_sz], 1);
    __syncthreads();
    for (int k = threadIdx.x; k < NB; k += 256)
        if (lc[k]) atomicAdd(&gcount[k], lc[k]);
}

__global__ __launch_bounds__(256) void k_scan512(const int* __restrict__ gcount,
                                                 int* __restrict__ gbase,
                                                 int* __restrict__ gcur, int E) {
    __shared__ int sA[NB], sB[NB];
    int tid = threadIdx.x;
    int c0 = gcount[tid], c1 = gcount[tid + 256];
    sA[tid] = c0; sA[tid + 256] = c1;
    __syncthreads();
    int* a = sA; int* bb = sB;
    for (int off = 1; off < NB; off <<= 1) {
        for (int k = tid; k < NB; k += 256) {
            int v = a[k];
            if (k >= off) v += a[k - off];
            bb[k] = v;
        }
        __syncthreads();
        int* t_ = a; a = bb; bb = t_;
    }
    int e0 = a[tid] - c0, e1 = a[tid + 256] - c1;
    gbase[tid] = e0;       gbase[tid + 256] = e1;
    gcur[tid] = e0;        gcur[tid + 256] = e1;
    if (tid == 0) gbase[NB] = E;
}

// packed pair: (src << 8) | (dst - bucket_base); nb_sz<=256 so local dst fits 8 bits
__global__ __launch_bounds__(256) void k_partition(const int* __restrict__ src,
                                                   const int* __restrict__ dst,
                                                   int* __restrict__ gcur,
                                                   unsigned int* __restrict__ pairs,
                                                   int E, int nb_sz) {
    __shared__ unsigned int stage[PCH];
    __shared__ int sA[NB], sB[NB], ofs[NB + 1], cur[NB], rbase[NB];
    int tid = threadIdx.x;
    int e0 = blockIdx.x * PCH;
    int m = E - e0; if (m > PCH) m = PCH;

    for (int k = tid; k < NB; k += 256) sA[k] = 0;
    __syncthreads();
    for (int i = tid; i < m; i += 256)
        atomicAdd(&sA[dst[e0 + i] / nb_sz], 1);
    __syncthreads();
    int c0 = sA[tid], c1 = sA[tid + 256];
    int* a = sA; int* bb = sB;
    for (int off = 1; off < NB; off <<= 1) {
        for (int k = tid; k < NB; k += 256) {
            int v = a[k];
            if (k >= off) v += a[k - off];
            bb[k] = v;
        }
        __syncthreads();
        int* t_ = a; a = bb; bb = t_;
    }
    int x0 = a[tid] - c0, x1 = a[tid + 256] - c1;
    ofs[tid] = x0;       ofs[tid + 256] = x1;
    cur[tid] = x0;       cur[tid + 256] = x1;
    if (tid == 0) ofs[NB] = m;
    __syncthreads();
    for (int i = tid; i < m; i += 256) {
        int d = dst[e0 + i];
        int s = src[e0 + i];
        int b = d / nb_sz;
        int p = atomicAdd(&cur[b], 1);
        stage[p] = ((unsigned)s << 8) | (unsigned)(d - b * nb_sz);
    }
    __syncthreads();
    for (int k = tid; k < NB; k += 256) {
        int cnt = ofs[k + 1] - ofs[k];
        rbase[k] = cnt > 0 ? atomicAdd(&gcur[k], cnt) : 0;
    }
    __syncthreads();
    for (int i = tid; i < m; i += 256) {
        int lo = 0, hi = NB;
        while (hi - lo > 1) {
            int mid = (lo + hi) >> 1;
            if (ofs[mid] <= i) lo = mid; else hi = mid;
        }
        pairs[rbase[lo] + (i - ofs[lo])] = stage[i];
    }
}

// per-bucket counting sort -> csr (src only) + ptr (per-node END offsets)
__global__ __launch_bounds__(256) void k_csr_local(const unsigned int* __restrict__ pairs,
                                                   const int* __restrict__ gbase,
                                                   int* __restrict__ csr,
                                                   int* __restrict__ ptr,
                                                   int N, int nb_sz) {
    int b = blockIdx.x;
    int n0 = b * nb_sz;
    if (n0 >= N) return;
    int n1 = n0 + nb_sz; if (n1 > N) n1 = N;
    int nn = n1 - n0;

    __shared__ int cnt[256], scn[256], cur[256];
    int tid = threadIdx.x;
    cnt[tid] = 0;
    __syncthreads();
    int s = gbase[b], e = gbase[b + 1];
    for (int i = s + tid; i < e; i += 256)
        atomicAdd(&cnt[pairs[i] & 0xFFu], 1);
    __syncthreads();
    int c = cnt[tid];
    scn[tid] = c;
    __syncthreads();
    for (int off = 1; off < 256; off <<= 1) {
        int mine = scn[tid];
        int add = (tid >= off) ? scn[tid - off] : 0;
        __syncthreads();
        scn[tid] = mine + add;
        __syncthreads();
    }
    cur[tid] = scn[tid] - c;                      // exclusive prefix
    if (tid < nn) ptr[n0 + tid] = s + scn[tid];   // end offset
    __syncthreads();
    for (int i = s + tid; i < e; i += 256) {
        unsigned int p = pairs[i];
        int pos = atomicAdd(&cur[p & 0xFFu], 1);
        csr[s + pos] = (int)(p >> 8);
    }
}

// ---------------- atomic-free per-node gathers ----------------

__global__ __launch_bounds__(256) void k_gather32(const unsigned short* __restrict__ t,
                                                  const int* __restrict__ csr,
                                                  const int* __restrict__ ptr,
                                                  float* __restrict__ agg, int n) {
    int tid = blockIdx.x * blockDim.x + threadIdx.x;
    int node = tid >> 5;
    int f = tid & 31;
    if (node >= n) return;
    int start = node ? ptr[node - 1] : 0;
    int end = ptr[node];
    float acc = 0.f;
    int j = start;
    for (; j + 3 < end; j += 4) {
        int s0 = csr[j], s1 = csr[j + 1], s2 = csr[j + 2], s3 = csr[j + 3];
        float v0 = bf2f(t[s0 * 32 + f]);
        float v1 = bf2f(t[s1 * 32 + f]);
        float v2 = bf2f(t[s2 * 32 + f]);
        float v3 = bf2f(t[s3 * 32 + f]);
        acc += v0; acc += v1; acc += v2; acc += v3;
    }
    for (; j < end; j++)
        acc += bf2f(t[csr[j] * 32 + f]);
    agg[(long long)node * 32 + f] = acc;
}

__global__ void k_gather2_out(const float* __restrict__ t3,
                              const int* __restrict__ csr,
                              const int* __restrict__ ptr,
                              const float* __restrict__ b3,
                              float* __restrict__ out, int n) {
    int node = blockIdx.x * blockDim.x + threadIdx.x;
    if (node >= n) return;
    int start = node ? ptr[node - 1] : 0;
    int end = ptr[node];
    float a0 = 0.f, a1 = 0.f;
    int j = start;
    for (; j + 1 < end; j += 2) {
        int s0 = csr[j], s1 = csr[j + 1];
        float2 v0 = *reinterpret_cast<const float2*>(t3 + (long long)s0 * 2);
        float2 v1 = *reinterpret_cast<const float2*>(t3 + (long long)s1 * 2);
        a0 += v0.x + v1.x;
        a1 += v0.y + v1.y;
    }
    if (j < end) {
        float2 v = *reinterpret_cast<const float2*>(t3 + (long long)csr[j] * 2);
        a0 += v.x; a1 += v.y;
    }
    float2* o = reinterpret_cast<float2*>(out + (long long)node * 2);
    *o = make_float2(a0 + b3[0], a1 + b3[1]);
}

// ---------------- graph embedding + prediction ----------------

__global__ void k_bounds(const int* __restrict__ gids, int n, int* __restrict__ start) {
    int g = threadIdx.x;
    if (g > N_GRAPHS) return;
    int lo = 0, hi = n;
    while (lo < hi) {
        int mid = (lo + hi) >> 1;
        if (gids[mid] < g) lo = mid + 1; else hi = mid;
    }
    start[g] = lo;
}

// chunk-parallel per-graph SUM of node features into ge (f32 atomics per block+graph)
__global__ __launch_bounds__(256) void k_gsum2(const float* __restrict__ nf,
                                               const int* __restrict__ gids,
                                               const int* __restrict__ gstart,
                                               float* __restrict__ ge, int N) {
    int c0 = blockIdx.x * GCH;
    if (c0 >= N) return;
    int c1 = c0 + GCH; if (c1 > N) c1 = N;
    int tid = threadIdx.x;
    int ng = tid >> 4;    // node group 0..15
    int f4 = tid & 15;    // float4 column

    int gfirst = gids[c0];
    int glast  = gids[c1 - 1];

    __shared__ float4 red[256];
    for (int g = gfirst; g <= glast; g++) {
        int s = gstart[g];     if (s < c0) s = c0;
        int e = gstart[g + 1]; if (e > c1) e = c1;
        float4 acc = make_float4(0.f, 0.f, 0.f, 0.f);
        for (int i = s + ng; i < e; i += 16) {
            float4 v = *reinterpret_cast<const float4*>(nf + (long long)i * IN_FEATS + f4 * 4);
            acc.x += v.x; acc.y += v.y; acc.z += v.z; acc.w += v.w;
        }
        red[tid] = acc;
        __syncthreads();
        for (int off = 8; off > 0; off >>= 1) {
            if (ng < off) {
                float4 o = red[(ng + off) * 16 + f4];
                float4 m = red[tid];
                m.x += o.x; m.y += o.y; m.z += o.z; m.w += o.w;
                red[tid] = m;
            }
            __syncthreads();
        }
        if (ng == 0 && e > s) {
            float4 m = red[f4];
            atomicAdd(&ge[g * IN_FEATS + f4 * 4 + 0], m.x);
            atomicAdd(&ge[g * IN_FEATS + f4 * 4 + 1], m.y);
            atomicAdd(&ge[g * IN_FEATS + f4 * 4 + 2], m.z);
            atomicAdd(&ge[g * IN_FEATS + f4 * 4 + 3], m.w);
        }
        __syncthreads();
    }
}

// prediction = sigmoid((ge_sum/count) @ Wl + bl)
__global__ void k_pred(const float* __restrict__ ge,
                       const int* __restrict__ gstart,
                       const float* __restrict__ Wl,
                       const float* __restrict__ bl,
                       float* __restrict__ out) {
    int g = threadIdx.x;
    if (g >= N_GRAPHS) return;
    float cnt = (float)(gstart[g + 1] - gstart[g]);
    float inv = 1.f / fmaxf(cnt, 1.0f);
    float acc = 0.f;
    for (int k = 0; k < IN_FEATS; k++)
        acc += ge[g * IN_FEATS + k] * Wl[k];
    acc = acc * inv + bl[0];
    out[g] = 1.f / (1.f + expf(-acc));
}

extern "C" void kernel_launch(void* const* d_in, const int* in_sizes, int n_in,
                              void* d_out, int out_size, void* d_ws, size_t ws_size,
                              hipStream_t stream) {
    const float* nf = (const float*)d_in[0];   // node_feats f32 [N,64]
    const float* W1 = (const float*)d_in[2];   // [64,32]
    const float* b1 = (const float*)d_in[3];   // [32]
    const float* W2 = (const float*)d_in[4];   // [32,32]
    const float* b2 = (const float*)d_in[5];   // [32]
    const float* W3 = (const float*)d_in[6];   // [32,2]
    const float* b3 = (const float*)d_in[7];   // [2]
    const float* Wl = (const float*)d_in[8];   // [64,1]
    const float* bl = (const float*)d_in[9];   // [1]
    const int* src  = (const int*)d_in[10];
    const int* dst  = (const int*)d_in[11];
    const int* gids = (const int*)d_in[12];

    const int N = in_sizes[0] / IN_FEATS;     // 100000
    const int E = in_sizes[10];               // 1600000
    const int nb_sz = (N + NB - 1) / NB;      // 196 (<=256 required for packing)

    float* out = (float*)d_out;

    // workspace layout:
    unsigned short* tb = (unsigned short*)d_ws;            // [N,32] bf16 (6.4MB)
    float* agg   = (float*)(tb + (size_t)N * HIDDEN);      // [N,32] f32 (12.8MB)
    float* t3    = agg + (size_t)N * HIDDEN;               // [N,2]  f32 (0.8MB)
    unsigned int* pairs = (unsigned int*)(t3 + (size_t)N * OUT_DIM); // [E] packed (6.4MB)
    int* csr     = (int*)(pairs + E);                      // [E] (6.4MB)
    int* ptr     = csr + E;                                // [N]
    int* gcount  = ptr + N;                                // [NB]
    int* gbase   = gcount + NB;                            // [NB+1]
    int* gcur    = gbase + NB + 1;                         // [NB]
    float* ge    = (float*)(gcur + NB);                    // [64,64]
    int* gstart  = (int*)(ge + N_GRAPHS * IN_FEATS);       // [65]

    const int TB = 256;
    int nodeBlocks = (N + TB - 1) / TB;
    int partBlocks = (E + PCH - 1) / PCH;
    int g32Blocks = (N * 32 + TB - 1) / TB;
    int gsumBlocks = (N + GCH - 1) / GCH;

    // ---- graph embedding prerequisites (independent of GCN chain) ----
    hipMemsetAsync(ge, 0, N_GRAPHS * IN_FEATS * sizeof(float), stream);
    k_bounds<<<1, 128, 0, stream>>>(gids, N, gstart);
    k_gsum2<<<gsumBlocks, TB, 0, stream>>>(nf, gids, gstart, ge, N);
    k_pred<<<1, 64, 0, stream>>>(ge, gstart, Wl, bl, out);

    // ---- CSR build (once, reused for all 3 layers) ----
    hipMemsetAsync(gcount, 0, NB * sizeof(int), stream);
    k_hist<<<256, TB, 0, stream>>>(dst, gcount, E, nb_sz);
    k_scan512<<<1, TB, 0, stream>>>(gcount, gbase, gcur, E);
    k_partition<<<partBlocks, TB, 0, stream>>>(src, dst, gcur, pairs, E, nb_sz);
    k_csr_local<<<NB, TB, 0, stream>>>(pairs, gbase, csr, ptr, N, nb_sz);

    // ---- layer 1 ----
    k_lin1<<<nodeBlocks, TB, 0, stream>>>(nf, W1, tb, N);
    k_gather32<<<g32Blocks, TB, 0, stream>>>(tb, csr, ptr, agg, N);

    // ---- layer 2 ----
    k_lin2<<<nodeBlocks, TB, 0, stream>>>(agg, b1, W2, tb, N);
    k_gather32<<<g32Blocks, TB, 0, stream>>>(tb, csr, ptr, agg, N);

    // ---- layer 3 ----
    k_lin3<<<nodeBlocks, TB, 0, stream>>>(agg, b2, W3, t3, N);
    k_gather2_out<<<nodeBlocks, TB, 0, stream>>>(t3, csr, ptr, b3, out + N_GRAPHS, N);
}

// Round 7
// 398.452 us; speedup vs baseline: 2.3205x; 1.0192x over previous
//
#include <hip/hip_runtime.h>
#include <hip/hip_bf16.h>

#define N_GRAPHS 64
#define IN_FEATS 64
#define HIDDEN 32
#define OUT_DIM 2

#define NB 512        // dst-range buckets
#define PCH 8192      // edges per partition block (LDS stage = 32 KB packed)
#define GCH 256       // nodes per k_gsum2 chunk

__device__ __forceinline__ float bf2f(unsigned short u) {
    unsigned int x = ((unsigned int)u) << 16;
    float f;
    __builtin_memcpy(&f, &x, 4);
    return f;
}

__device__ __forceinline__ unsigned short f2bf(float f) {
    __hip_bfloat16 h = __float2bfloat16(f);   // RNE
    unsigned short u;
    __builtin_memcpy(&u, &h, 2);
    return u;
}

// ---------------- dense linears (node-parallel) ----------------
// t written as TWO feature slabs t0,t1: [N,16] bf16 each (3.2 MB — fits XCD L2)

// t1 = node_feats(f32 [N,64]) @ W1(f32 [64,32]) -> slabs (bias deferred)
__global__ void k_lin1(const float* __restrict__ nf,
                       const float* __restrict__ W,
                       unsigned short* __restrict__ t0,
                       unsigned short* __restrict__ t1, int n) {
    __shared__ float w[IN_FEATS * HIDDEN];
    for (int i = threadIdx.x; i < IN_FEATS * HIDDEN; i += blockDim.x)
        w[i] = W[i];
    __syncthreads();
    int row = blockIdx.x * blockDim.x + threadIdx.x;
    if (row >= n) return;

    float a[IN_FEATS];
    const float4* r4 = reinterpret_cast<const float4*>(nf + (long long)row * IN_FEATS);
    #pragma unroll
    for (int v = 0; v < IN_FEATS / 4; v++) {
        float4 q = r4[v];
        a[v * 4 + 0] = q.x; a[v * 4 + 1] = q.y; a[v * 4 + 2] = q.z; a[v * 4 + 3] = q.w;
    }
    float acc[HIDDEN];
    #pragma unroll
    for (int f = 0; f < HIDDEN; f++) acc[f] = 0.f;
    for (int k = 0; k < IN_FEATS; k++) {
        float av = a[k];
        #pragma unroll
        for (int f = 0; f < HIDDEN; f++) acc[f] += av * w[k * HIDDEN + f];
    }
    unsigned int packed[HIDDEN / 2];
    #pragma unroll
    for (int f = 0; f < HIDDEN / 2; f++)
        packed[f] = (unsigned int)f2bf(acc[2 * f]) | ((unsigned int)f2bf(acc[2 * f + 1]) << 16);
    uint4* o0 = reinterpret_cast<uint4*>(t0 + (long long)row * 16);
    uint4* o1 = reinterpret_cast<uint4*>(t1 + (long long)row * 16);
    o0[0] = make_uint4(packed[0], packed[1], packed[2], packed[3]);
    o0[1] = make_uint4(packed[4], packed[5], packed[6], packed[7]);
    o1[0] = make_uint4(packed[8], packed[9], packed[10], packed[11]);
    o1[1] = make_uint4(packed[12], packed[13], packed[14], packed[15]);
}

// t2 = (agg(f32 [N,32]) + b[32]) @ W(f32 [32,32]) -> slabs
__global__ void k_lin2(const float* __restrict__ in,
                       const float* __restrict__ b,
                       const float* __restrict__ W,
                       unsigned short* __restrict__ t0,
                       unsigned short* __restrict__ t1, int n) {
    __shared__ float w[HIDDEN * HIDDEN];
    __shared__ float bs[HIDDEN];
    for (int i = threadIdx.x; i < HIDDEN * HIDDEN; i += blockDim.x) w[i] = W[i];
    if (threadIdx.x < HIDDEN) bs[threadIdx.x] = b[threadIdx.x];
    __syncthreads();
    int row = blockIdx.x * blockDim.x + threadIdx.x;
    if (row >= n) return;

    float a[HIDDEN];
    const float4* r4 = reinterpret_cast<const float4*>(in + (long long)row * HIDDEN);
    #pragma unroll
    for (int v = 0; v < HIDDEN / 4; v++) {
        float4 q = r4[v];
        a[v * 4 + 0] = q.x; a[v * 4 + 1] = q.y; a[v * 4 + 2] = q.z; a[v * 4 + 3] = q.w;
    }
    #pragma unroll
    for (int k = 0; k < HIDDEN; k++) a[k] += bs[k];
    float acc[HIDDEN];
    #pragma unroll
    for (int f = 0; f < HIDDEN; f++) acc[f] = 0.f;
    for (int k = 0; k < HIDDEN; k++) {
        float av = a[k];
        #pragma unroll
        for (int f = 0; f < HIDDEN; f++) acc[f] += av * w[k * HIDDEN + f];
    }
    unsigned int packed[HIDDEN / 2];
    #pragma unroll
    for (int f = 0; f < HIDDEN / 2; f++)
        packed[f] = (unsigned int)f2bf(acc[2 * f]) | ((unsigned int)f2bf(acc[2 * f + 1]) << 16);
    uint4* o0 = reinterpret_cast<uint4*>(t0 + (long long)row * 16);
    uint4* o1 = reinterpret_cast<uint4*>(t1 + (long long)row * 16);
    o0[0] = make_uint4(packed[0], packed[1], packed[2], packed[3]);
    o0[1] = make_uint4(packed[4], packed[5], packed[6], packed[7]);
    o1[0] = make_uint4(packed[8], packed[9], packed[10], packed[11]);
    o1[1] = make_uint4(packed[12], packed[13], packed[14], packed[15]);
}

// t3 = (agg2 + b2) @ W3(f32 [32,2]) -> f32 [N,2]
__global__ void k_lin3(const float* __restrict__ in,
                       const float* __restrict__ b,
                       const float* __restrict__ W,
                       float* __restrict__ out, int n) {
    __shared__ float w[HIDDEN * OUT_DIM];
    __shared__ float bs[HIDDEN];
    for (int i = threadIdx.x; i < HIDDEN * OUT_DIM; i += blockDim.x) w[i] = W[i];
    if (threadIdx.x < HIDDEN) bs[threadIdx.x] = b[threadIdx.x];
    __syncthreads();
    int row = blockIdx.x * blockDim.x + threadIdx.x;
    if (row >= n) return;

    const float4* r4 = reinterpret_cast<const float4*>(in + (long long)row * HIDDEN);
    float acc0 = 0.f, acc1 = 0.f;
    #pragma unroll
    for (int v = 0; v < HIDDEN / 4; v++) {
        float4 q = r4[v];
        float av;
        av = q.x + bs[v * 4 + 0]; acc0 += av * w[(v * 4 + 0) * 2]; acc1 += av * w[(v * 4 + 0) * 2 + 1];
        av = q.y + bs[v * 4 + 1]; acc0 += av * w[(v * 4 + 1) * 2]; acc1 += av * w[(v * 4 + 1) * 2 + 1];
        av = q.z + bs[v * 4 + 2]; acc0 += av * w[(v * 4 + 2) * 2]; acc1 += av * w[(v * 4 + 2) * 2 + 1];
        av = q.w + bs[v * 4 + 3]; acc0 += av * w[(v * 4 + 3) * 2]; acc1 += av * w[(v * 4 + 3) * 2 + 1];
    }
    float2* o = reinterpret_cast<float2*>(out + (long long)row * OUT_DIM);
    *o = make_float2(acc0, acc1);
}

// ---------------- CSR build: bucket partition + local counting sort ----------------

__global__ __launch_bounds__(256) void k_hist(const int* __restrict__ dst,
                                              int* __restrict__ gcount,
                                              int E, int nb_sz) {
    __shared__ int lc[NB];
    for (int k = threadIdx.x; k < NB; k += 256) lc[k] = 0;
    __syncthreads();
    int stride = gridDim.x * 256;
    for (int i = blockIdx.x * 256 + threadIdx.x; i < E; i += stride)
        atomicAdd(&lc[dst[i] / nb_sz], 1);
    __syncthreads();
    for (int k = threadIdx.x; k < NB; k += 256)
        if (lc[k]) atomicAdd(&gcount[k], lc[k]);
}

__global__ __launch_bounds__(256) void k_scan512(const int* __restrict__ gcount,
                                                 int* __restrict__ gbase,
                                                 int* __restrict__ gcur, int E) {
    __shared__ int sA[NB], sB[NB];
    int tid = threadIdx.x;
    int c0 = gcount[tid], c1 = gcount[tid + 256];
    sA[tid] = c0; sA[tid + 256] = c1;
    __syncthreads();
    int* a = sA; int* bb = sB;
    for (int off = 1; off < NB; off <<= 1) {
        for (int k = tid; k < NB; k += 256) {
            int v = a[k];
            if (k >= off) v += a[k - off];
            bb[k] = v;
        }
        __syncthreads();
        int* t_ = a; a = bb; bb = t_;
    }
    int e0 = a[tid] - c0, e1 = a[tid + 256] - c1;
    gbase[tid] = e0;       gbase[tid + 256] = e1;
    gcur[tid] = e0;        gcur[tid + 256] = e1;
    if (tid == 0) gbase[NB] = E;
}

// packed pair: (src << 8) | (dst - bucket_base); nb_sz<=256 so local dst fits 8 bits
__global__ __launch_bounds__(256) void k_partition(const int* __restrict__ src,
                                                   const int* __restrict__ dst,
                                                   int* __restrict__ gcur,
                                                   unsigned int* __restrict__ pairs,
                                                   int E, int nb_sz) {
    __shared__ unsigned int stage[PCH];
    __shared__ int sA[NB], sB[NB], ofs[NB + 1], cur[NB], rbase[NB];
    int tid = threadIdx.x;
    int e0 = blockIdx.x * PCH;
    int m = E - e0; if (m > PCH) m = PCH;

    for (int k = tid; k < NB; k += 256) sA[k] = 0;
    __syncthreads();
    for (int i = tid; i < m; i += 256)
        atomicAdd(&sA[dst[e0 + i] / nb_sz], 1);
    __syncthreads();
    int c0 = sA[tid], c1 = sA[tid + 256];
    int* a = sA; int* bb = sB;
    for (int off = 1; off < NB; off <<= 1) {
        for (int k = tid; k < NB; k += 256) {
            int v = a[k];
            if (k >= off) v += a[k - off];
            bb[k] = v;
        }
        __syncthreads();
        int* t_ = a; a = bb; bb = t_;
    }
    int x0 = a[tid] - c0, x1 = a[tid + 256] - c1;
    ofs[tid] = x0;       ofs[tid + 256] = x1;
    cur[tid] = x0;       cur[tid + 256] = x1;
    if (tid == 0) ofs[NB] = m;
    __syncthreads();
    for (int i = tid; i < m; i += 256) {
        int d = dst[e0 + i];
        int s = src[e0 + i];
        int b = d / nb_sz;
        int p = atomicAdd(&cur[b], 1);
        stage[p] = ((unsigned)s << 8) | (unsigned)(d - b * nb_sz);
    }
    __syncthreads();
    for (int k = tid; k < NB; k += 256) {
        int cnt = ofs[k + 1] - ofs[k];
        rbase[k] = cnt > 0 ? atomicAdd(&gcur[k], cnt) : 0;
    }
    __syncthreads();
    for (int i = tid; i < m; i += 256) {
        int lo = 0, hi = NB;
        while (hi - lo > 1) {
            int mid = (lo + hi) >> 1;
            if (ofs[mid] <= i) lo = mid; else hi = mid;
        }
        pairs[rbase[lo] + (i - ofs[lo])] = stage[i];
    }
}

// per-bucket counting sort -> csr (src only) + ptr (per-node END offsets)
__global__ __launch_bounds__(256) void k_csr_local(const unsigned int* __restrict__ pairs,
                                                   const int* __restrict__ gbase,
                                                   int* __restrict__ csr,
                                                   int* __restrict__ ptr,
                                                   int N, int nb_sz) {
    int b = blockIdx.x;
    int n0 = b * nb_sz;
    if (n0 >= N) return;
    int n1 = n0 + nb_sz; if (n1 > N) n1 = N;
    int nn = n1 - n0;

    __shared__ int cnt[256], scn[256], cur[256];
    int tid = threadIdx.x;
    cnt[tid] = 0;
    __syncthreads();
    int s = gbase[b], e = gbase[b + 1];
    for (int i = s + tid; i < e; i += 256)
        atomicAdd(&cnt[pairs[i] & 0xFFu], 1);
    __syncthreads();
    int c = cnt[tid];
    scn[tid] = c;
    __syncthreads();
    for (int off = 1; off < 256; off <<= 1) {
        int mine = scn[tid];
        int add = (tid >= off) ? scn[tid - off] : 0;
        __syncthreads();
        scn[tid] = mine + add;
        __syncthreads();
    }
    cur[tid] = scn[tid] - c;                      // exclusive prefix
    if (tid < nn) ptr[n0 + tid] = s + scn[tid];   // end offset
    __syncthreads();
    for (int i = s + tid; i < e; i += 256) {
        unsigned int p = pairs[i];
        int pos = atomicAdd(&cur[p & 0xFFu], 1);
        csr[s + pos] = (int)(p >> 8);
    }
}

// ---------------- atomic-free per-node slab gathers ----------------

// one slab pass: agg[node][half*16 + 2*lf .. +1] = sum over in-edges of t16[src][2*lf..+1]
// 8 lanes per node; lane loads uint (2 bf16); slab is 3.2 MB -> XCD-L2 resident
__global__ __launch_bounds__(256) void k_gather16(const unsigned short* __restrict__ t16,
                                                  const int* __restrict__ csr,
                                                  const int* __restrict__ ptr,
                                                  float* __restrict__ agg,
                                                  int half, int n) {
    int tid = blockIdx.x * blockDim.x + threadIdx.x;
    int node = tid >> 3;
    int lf = tid & 7;
    if (node >= n) return;
    int start = node ? ptr[node - 1] : 0;
    int end = ptr[node];
    float a0 = 0.f, a1 = 0.f;
    int j = start;
    for (; j + 3 < end; j += 4) {
        int s0 = csr[j], s1 = csr[j + 1], s2 = csr[j + 2], s3 = csr[j + 3];
        unsigned int u0 = *reinterpret_cast<const unsigned int*>(t16 + s0 * 16 + lf * 2);
        unsigned int u1 = *reinterpret_cast<const unsigned int*>(t16 + s1 * 16 + lf * 2);
        unsigned int u2 = *reinterpret_cast<const unsigned int*>(t16 + s2 * 16 + lf * 2);
        unsigned int u3 = *reinterpret_cast<const unsigned int*>(t16 + s3 * 16 + lf * 2);
        a0 += bf2f((unsigned short)(u0 & 0xffffu)) + bf2f((unsigned short)(u1 & 0xffffu));
        a1 += bf2f((unsigned short)(u0 >> 16))     + bf2f((unsigned short)(u1 >> 16));
        a0 += bf2f((unsigned short)(u2 & 0xffffu)) + bf2f((unsigned short)(u3 & 0xffffu));
        a1 += bf2f((unsigned short)(u2 >> 16))     + bf2f((unsigned short)(u3 >> 16));
    }
    for (; j < end; j++) {
        unsigned int u = *reinterpret_cast<const unsigned int*>(t16 + csr[j] * 16 + lf * 2);
        a0 += bf2f((unsigned short)(u & 0xffffu));
        a1 += bf2f((unsigned short)(u >> 16));
    }
    float2* o = reinterpret_cast<float2*>(agg + (long long)node * 32 + half * 16 + lf * 2);
    *o = make_float2(a0, a1);
}

// layer-3 gather (2 f32 feats) + bias, straight into d_out
__global__ void k_gather2_out(const float* __restrict__ t3,
                              const int* __restrict__ csr,
                              const int* __restrict__ ptr,
                              const float* __restrict__ b3,
                              float* __restrict__ out, int n) {
    int node = blockIdx.x * blockDim.x + threadIdx.x;
    if (node >= n) return;
    int start = node ? ptr[node - 1] : 0;
    int end = ptr[node];
    float a0 = 0.f, a1 = 0.f;
    int j = start;
    for (; j + 1 < end; j += 2) {
        int s0 = csr[j], s1 = csr[j + 1];
        float2 v0 = *reinterpret_cast<const float2*>(t3 + (long long)s0 * 2);
        float2 v1 = *reinterpret_cast<const float2*>(t3 + (long long)s1 * 2);
        a0 += v0.x + v1.x;
        a1 += v0.y + v1.y;
    }
    if (j < end) {
        float2 v = *reinterpret_cast<const float2*>(t3 + (long long)csr[j] * 2);
        a0 += v.x; a1 += v.y;
    }
    float2* o = reinterpret_cast<float2*>(out + (long long)node * 2);
    *o = make_float2(a0 + b3[0], a1 + b3[1]);
}

// ---------------- graph embedding + prediction ----------------

__global__ void k_bounds(const int* __restrict__ gids, int n, int* __restrict__ start) {
    int g = threadIdx.x;
    if (g > N_GRAPHS) return;
    int lo = 0, hi = n;
    while (lo < hi) {
        int mid = (lo + hi) >> 1;
        if (gids[mid] < g) lo = mid + 1; else hi = mid;
    }
    start[g] = lo;
}

// chunk-parallel per-graph SUM of node features into ge (f32 atomics per block+graph)
__global__ __launch_bounds__(256) void k_gsum2(const float* __restrict__ nf,
                                               const int* __restrict__ gids,
                                               const int* __restrict__ gstart,
                                               float* __restrict__ ge, int N) {
    int c0 = blockIdx.x * GCH;
    if (c0 >= N) return;
    int c1 = c0 + GCH; if (c1 > N) c1 = N;
    int tid = threadIdx.x;
    int ng = tid >> 4;    // node group 0..15
    int f4 = tid & 15;    // float4 column

    int gfirst = gids[c0];
    int glast  = gids[c1 - 1];

    __shared__ float4 red[256];
    for (int g = gfirst; g <= glast; g++) {
        int s = gstart[g];     if (s < c0) s = c0;
        int e = gstart[g + 1]; if (e > c1) e = c1;
        float4 acc = make_float4(0.f, 0.f, 0.f, 0.f);
        for (int i = s + ng; i < e; i += 16) {
            float4 v = *reinterpret_cast<const float4*>(nf + (long long)i * IN_FEATS + f4 * 4);
            acc.x += v.x; acc.y += v.y; acc.z += v.z; acc.w += v.w;
        }
        red[tid] = acc;
        __syncthreads();
        for (int off = 8; off > 0; off >>= 1) {
            if (ng < off) {
                float4 o = red[(ng + off) * 16 + f4];
                float4 m = red[tid];
                m.x += o.x; m.y += o.y; m.z += o.z; m.w += o.w;
                red[tid] = m;
            }
            __syncthreads();
        }
        if (ng == 0 && e > s) {
            float4 m = red[f4];
            atomicAdd(&ge[g * IN_FEATS + f4 * 4 + 0], m.x);
            atomicAdd(&ge[g * IN_FEATS + f4 * 4 + 1], m.y);
            atomicAdd(&ge[g * IN_FEATS + f4 * 4 + 2], m.z);
            atomicAdd(&ge[g * IN_FEATS + f4 * 4 + 3], m.w);
        }
        __syncthreads();
    }
}

// prediction = sigmoid((ge_sum/count) @ Wl + bl)
__global__ void k_pred(const float* __restrict__ ge,
                       const int* __restrict__ gstart,
                       const float* __restrict__ Wl,
                       const float* __restrict__ bl,
                       float* __restrict__ out) {
    int g = threadIdx.x;
    if (g >= N_GRAPHS) return;
    float cnt = (float)(gstart[g + 1] - gstart[g]);
    float inv = 1.f / fmaxf(cnt, 1.0f);
    float acc = 0.f;
    for (int k = 0; k < IN_FEATS; k++)
        acc += ge[g * IN_FEATS + k] * Wl[k];
    acc = acc * inv + bl[0];
    out[g] = 1.f / (1.f + expf(-acc));
}

extern "C" void kernel_launch(void* const* d_in, const int* in_sizes, int n_in,
                              void* d_out, int out_size, void* d_ws, size_t ws_size,
                              hipStream_t stream) {
    const float* nf = (const float*)d_in[0];   // node_feats f32 [N,64]
    const float* W1 = (const float*)d_in[2];   // [64,32]
    const float* b1 = (const float*)d_in[3];   // [32]
    const float* W2 = (const float*)d_in[4];   // [32,32]
    const float* b2 = (const float*)d_in[5];   // [32]
    const float* W3 = (const float*)d_in[6];   // [32,2]
    const float* b3 = (const float*)d_in[7];   // [2]
    const float* Wl = (const float*)d_in[8];   // [64,1]
    const float* bl = (const float*)d_in[9];   // [1]
    const int* src  = (const int*)d_in[10];
    const int* dst  = (const int*)d_in[11];
    const int* gids = (const int*)d_in[12];

    const int N = in_sizes[0] / IN_FEATS;     // 100000
    const int E = in_sizes[10];               // 1600000
    const int nb_sz = (N + NB - 1) / NB;      // 196 (<=256 required for packing)

    float* out = (float*)d_out;

    // workspace layout:
    unsigned short* t0 = (unsigned short*)d_ws;            // slab0 [N,16] bf16 (3.2MB)
    unsigned short* t1 = t0 + (size_t)N * 16;              // slab1 [N,16] bf16 (3.2MB)
    float* agg   = (float*)(t1 + (size_t)N * 16);          // [N,32] f32 (12.8MB)
    float* t3    = agg + (size_t)N * HIDDEN;               // [N,2]  f32 (0.8MB)
    unsigned int* pairs = (unsigned int*)(t3 + (size_t)N * OUT_DIM); // [E] packed (6.4MB)
    int* csr     = (int*)(pairs + E);                      // [E] (6.4MB)
    int* ptr     = csr + E;                                // [N]
    int* gcount  = ptr + N;                                // [NB]
    int* gbase   = gcount + NB;                            // [NB+1]
    int* gcur    = gbase + NB + 1;                         // [NB]
    float* ge    = (float*)(gcur + NB);                    // [64,64]
    int* gstart  = (int*)(ge + N_GRAPHS * IN_FEATS);       // [65]

    const int TB = 256;
    int nodeBlocks = (N + TB - 1) / TB;
    int partBlocks = (E + PCH - 1) / PCH;
    int g16Blocks = (N * 8 + TB - 1) / TB;
    int gsumBlocks = (N + GCH - 1) / GCH;

    // ---- graph embedding prerequisites (independent of GCN chain) ----
    hipMemsetAsync(ge, 0, N_GRAPHS * IN_FEATS * sizeof(float), stream);
    k_bounds<<<1, 128, 0, stream>>>(gids, N, gstart);
    k_gsum2<<<gsumBlocks, TB, 0, stream>>>(nf, gids, gstart, ge, N);
    k_pred<<<1, 64, 0, stream>>>(ge, gstart, Wl, bl, out);

    // ---- CSR build (once, reused for all 3 layers) ----
    hipMemsetAsync(gcount, 0, NB * sizeof(int), stream);
    k_hist<<<256, TB, 0, stream>>>(dst, gcount, E, nb_sz);
    k_scan512<<<1, TB, 0, stream>>>(gcount, gbase, gcur, E);
    k_partition<<<partBlocks, TB, 0, stream>>>(src, dst, gcur, pairs, E, nb_sz);
    k_csr_local<<<NB, TB, 0, stream>>>(pairs, gbase, csr, ptr, N, nb_sz);

    // ---- layer 1 ----
    k_lin1<<<nodeBlocks, TB, 0, stream>>>(nf, W1, t0, t1, N);
    k_gather16<<<g16Blocks, TB, 0, stream>>>(t0, csr, ptr, agg, 0, N);
    k_gather16<<<g16Blocks, TB, 0, stream>>>(t1, csr, ptr, agg, 1, N);

    // ---- layer 2 ----
    k_lin2<<<nodeBlocks, TB, 0, stream>>>(agg, b1, W2, t0, t1, N);
    k_gather16<<<g16Blocks, TB, 0, stream>>>(t0, csr, ptr, agg, 0, N);
    k_gather16<<<g16Blocks, TB, 0, stream>>>(t1, csr, ptr, agg, 1, N);

    // ---- layer 3 ----
    k_lin3<<<nodeBlocks, TB, 0, stream>>>(agg, b2, W3, t3, N);
    k_gather2_out<<<nodeBlocks, TB, 0, stream>>>(t3, csr, ptr, b3, out + N_GRAPHS, N);
}

// Round 8
// 374.009 us; speedup vs baseline: 2.4722x; 1.0654x over previous
//
#include <hip/hip_runtime.h>
#include <hip/hip_bf16.h>

#define N_GRAPHS 64
#define IN_FEATS 64
#define HIDDEN 32
#define OUT_DIM 2

#define NB 512        // dst-range buckets
#define PCH 8192      // edges per partition block (LDS stage = 32 KB packed)
#define GCH 256       // nodes per k_gsum2 chunk

__device__ __forceinline__ float bf2f(unsigned short u) {
    unsigned int x = ((unsigned int)u) << 16;
    float f;
    __builtin_memcpy(&f, &x, 4);
    return f;
}

__device__ __forceinline__ unsigned short f2bf(float f) {
    __hip_bfloat16 h = __float2bfloat16(f);   // RNE
    unsigned short u;
    __builtin_memcpy(&u, &h, 2);
    return u;
}

// ---------------- layer 1 linear (node-parallel) ----------------

// t = node_feats(f32 [N,64]) @ W1(f32 [64,32]) -> bf16 [N,32] (bias deferred)
__global__ void k_lin1(const float* __restrict__ nf,
                       const float* __restrict__ W,
                       unsigned int* __restrict__ t, int n) {
    __shared__ float w[IN_FEATS * HIDDEN];
    for (int i = threadIdx.x; i < IN_FEATS * HIDDEN; i += blockDim.x)
        w[i] = W[i];
    __syncthreads();
    int row = blockIdx.x * blockDim.x + threadIdx.x;
    if (row >= n) return;

    float a[IN_FEATS];
    const float4* r4 = reinterpret_cast<const float4*>(nf + (long long)row * IN_FEATS);
    #pragma unroll
    for (int v = 0; v < IN_FEATS / 4; v++) {
        float4 q = r4[v];
        a[v * 4 + 0] = q.x; a[v * 4 + 1] = q.y; a[v * 4 + 2] = q.z; a[v * 4 + 3] = q.w;
    }
    float acc[HIDDEN];
    #pragma unroll
    for (int f = 0; f < HIDDEN; f++) acc[f] = 0.f;
    for (int k = 0; k < IN_FEATS; k++) {
        float av = a[k];
        #pragma unroll
        for (int f = 0; f < HIDDEN; f++) acc[f] += av * w[k * HIDDEN + f];
    }
    unsigned int packed[HIDDEN / 2];
    #pragma unroll
    for (int f = 0; f < HIDDEN / 2; f++)
        packed[f] = (unsigned int)f2bf(acc[2 * f]) | ((unsigned int)f2bf(acc[2 * f + 1]) << 16);
    uint4* o = reinterpret_cast<uint4*>(t + (long long)row * 16);
    #pragma unroll
    for (int v = 0; v < 4; v++)
        o[v] = make_uint4(packed[v * 4], packed[v * 4 + 1], packed[v * 4 + 2], packed[v * 4 + 3]);
}

// ---------------- fused gather + linear ----------------

// 16 lanes per node: gather bf16 row from tin (agg), add b, @W (32x32), write bf16 to tout
__global__ __launch_bounds__(256) void k_gather_lin2(const unsigned int* __restrict__ tin,
                                                     const int* __restrict__ csr,
                                                     const int* __restrict__ ptr,
                                                     const float* __restrict__ b,
                                                     const float* __restrict__ W,
                                                     unsigned int* __restrict__ tout,
                                                     int n) {
    __shared__ float w[HIDDEN * HIDDEN];
    __shared__ float bs[HIDDEN];
    __shared__ float rows[16][HIDDEN + 1];   // +1 pad: matmul reads bank-spread
    int tid = threadIdx.x;
    for (int i = tid; i < HIDDEN * HIDDEN; i += 256) w[i] = W[i];
    if (tid < HIDDEN) bs[tid] = b[tid];
    __syncthreads();

    int g = tid >> 4;        // node group 0..15
    int l = tid & 15;        // lane within group (owns feats 2l, 2l+1)
    int node = blockIdx.x * 16 + g;
    bool act = node < n;

    if (act) {
        int start = node ? ptr[node - 1] : 0;
        int end = ptr[node];
        float a0 = 0.f, a1 = 0.f;
        int j = start;
        for (; j + 3 < end; j += 4) {
            int s0 = csr[j], s1 = csr[j + 1], s2 = csr[j + 2], s3 = csr[j + 3];
            unsigned int u0 = tin[s0 * 16 + l];
            unsigned int u1 = tin[s1 * 16 + l];
            unsigned int u2 = tin[s2 * 16 + l];
            unsigned int u3 = tin[s3 * 16 + l];
            a0 += bf2f((unsigned short)(u0 & 0xffffu)) + bf2f((unsigned short)(u1 & 0xffffu));
            a1 += bf2f((unsigned short)(u0 >> 16))     + bf2f((unsigned short)(u1 >> 16));
            a0 += bf2f((unsigned short)(u2 & 0xffffu)) + bf2f((unsigned short)(u3 & 0xffffu));
            a1 += bf2f((unsigned short)(u2 >> 16))     + bf2f((unsigned short)(u3 >> 16));
        }
        for (; j < end; j++) {
            unsigned int u = tin[csr[j] * 16 + l];
            a0 += bf2f((unsigned short)(u & 0xffffu));
            a1 += bf2f((unsigned short)(u >> 16));
        }
        rows[g][2 * l]     = a0 + bs[2 * l];
        rows[g][2 * l + 1] = a1 + bs[2 * l + 1];
    }
    __syncthreads();
    if (!act) return;

    const float2* wf2 = reinterpret_cast<const float2*>(w);
    float acc0 = 0.f, acc1 = 0.f;
    #pragma unroll
    for (int k = 0; k < HIDDEN; k++) {
        float rk = rows[g][k];
        float2 wk = wf2[k * 16 + l];
        acc0 += rk * wk.x;
        acc1 += rk * wk.y;
    }
    tout[node * 16 + l] = (unsigned int)f2bf(acc0) | ((unsigned int)f2bf(acc1) << 16);
}

// 16 lanes per node: gather row, add b2, @W3 (32x2) via shfl reduce -> t3 f32 [N,2]
__global__ __launch_bounds__(256) void k_gather_lin3(const unsigned int* __restrict__ tin,
                                                     const int* __restrict__ csr,
                                                     const int* __restrict__ ptr,
                                                     const float* __restrict__ b,
                                                     const float* __restrict__ W,
                                                     float* __restrict__ t3,
                                                     int n) {
    __shared__ float w[HIDDEN * OUT_DIM];
    __shared__ float bs[HIDDEN];
    int tid = threadIdx.x;
    if (tid < HIDDEN * OUT_DIM) w[tid] = W[tid];
    if (tid < HIDDEN) bs[tid] = b[tid];
    __syncthreads();

    int g = tid >> 4;
    int l = tid & 15;
    int node = blockIdx.x * 16 + g;
    if (node >= n) return;

    int start = node ? ptr[node - 1] : 0;
    int end = ptr[node];
    float a0 = 0.f, a1 = 0.f;
    int j = start;
    for (; j + 3 < end; j += 4) {
        int s0 = csr[j], s1 = csr[j + 1], s2 = csr[j + 2], s3 = csr[j + 3];
        unsigned int u0 = tin[s0 * 16 + l];
        unsigned int u1 = tin[s1 * 16 + l];
        unsigned int u2 = tin[s2 * 16 + l];
        unsigned int u3 = tin[s3 * 16 + l];
        a0 += bf2f((unsigned short)(u0 & 0xffffu)) + bf2f((unsigned short)(u1 & 0xffffu));
        a1 += bf2f((unsigned short)(u0 >> 16))     + bf2f((unsigned short)(u1 >> 16));
        a0 += bf2f((unsigned short)(u2 & 0xffffu)) + bf2f((unsigned short)(u3 & 0xffffu));
        a1 += bf2f((unsigned short)(u2 >> 16))     + bf2f((unsigned short)(u3 >> 16));
    }
    for (; j < end; j++) {
        unsigned int u = tin[csr[j] * 16 + l];
        a0 += bf2f((unsigned short)(u & 0xffffu));
        a1 += bf2f((unsigned short)(u >> 16));
    }
    float r0 = a0 + bs[2 * l], r1 = a1 + bs[2 * l + 1];
    float p0 = r0 * w[(2 * l) * 2 + 0] + r1 * w[(2 * l + 1) * 2 + 0];
    float p1 = r0 * w[(2 * l) * 2 + 1] + r1 * w[(2 * l + 1) * 2 + 1];
    #pragma unroll
    for (int off = 1; off < 16; off <<= 1) {
        p0 += __shfl_xor(p0, off);
        p1 += __shfl_xor(p1, off);
    }
    if (l == 0) {
        float2* o = reinterpret_cast<float2*>(t3 + (long long)node * 2);
        *o = make_float2(p0, p1);
    }
}

// ---------------- CSR build: bucket partition + local counting sort ----------------

__global__ __launch_bounds__(256) void k_hist(const int* __restrict__ dst,
                                              int* __restrict__ gcount,
                                              int E, int nb_sz) {
    __shared__ int lc[NB];
    for (int k = threadIdx.x; k < NB; k += 256) lc[k] = 0;
    __syncthreads();
    int stride = gridDim.x * 256;
    for (int i = blockIdx.x * 256 + threadIdx.x; i < E; i += stride)
        atomicAdd(&lc[dst[i] / nb_sz], 1);
    __syncthreads();
    for (int k = threadIdx.x; k < NB; k += 256)
        if (lc[k]) atomicAdd(&gcount[k], lc[k]);
}

__global__ __launch_bounds__(256) void k_scan512(const int* __restrict__ gcount,
                                                 int* __restrict__ gbase,
                                                 int* __restrict__ gcur, int E) {
    __shared__ int sA[NB], sB[NB];
    int tid = threadIdx.x;
    int c0 = gcount[tid], c1 = gcount[tid + 256];
    sA[tid] = c0; sA[tid + 256] = c1;
    __syncthreads();
    int* a = sA; int* bb = sB;
    for (int off = 1; off < NB; off <<= 1) {
        for (int k = tid; k < NB; k += 256) {
            int v = a[k];
            if (k >= off) v += a[k - off];
            bb[k] = v;
        }
        __syncthreads();
        int* t_ = a; a = bb; bb = t_;
    }
    int e0 = a[tid] - c0, e1 = a[tid + 256] - c1;
    gbase[tid] = e0;       gbase[tid + 256] = e1;
    gcur[tid] = e0;        gcur[tid + 256] = e1;
    if (tid == 0) gbase[NB] = E;
}

// packed pair: (src << 8) | (dst - bucket_base); nb_sz<=256 so local dst fits 8 bits
__global__ __launch_bounds__(256) void k_partition(const int* __restrict__ src,
                                                   const int* __restrict__ dst,
                                                   int* __restrict__ gcur,
                                                   unsigned int* __restrict__ pairs,
                                                   int E, int nb_sz) {
    __shared__ unsigned int stage[PCH];
    __shared__ int sA[NB], sB[NB], ofs[NB + 1], cur[NB], rbase[NB];
    int tid = threadIdx.x;
    int e0 = blockIdx.x * PCH;
    int m = E - e0; if (m > PCH) m = PCH;

    for (int k = tid; k < NB; k += 256) sA[k] = 0;
    __syncthreads();
    for (int i = tid; i < m; i += 256)
        atomicAdd(&sA[dst[e0 + i] / nb_sz], 1);
    __syncthreads();
    int c0 = sA[tid], c1 = sA[tid + 256];
    int* a = sA; int* bb = sB;
    for (int off = 1; off < NB; off <<= 1) {
        for (int k = tid; k < NB; k += 256) {
            int v = a[k];
            if (k >= off) v += a[k - off];
            bb[k] = v;
        }
        __syncthreads();
        int* t_ = a; a = bb; bb = t_;
    }
    int x0 = a[tid] - c0, x1 = a[tid + 256] - c1;
    ofs[tid] = x0;       ofs[tid + 256] = x1;
    cur[tid] = x0;       cur[tid + 256] = x1;
    if (tid == 0) ofs[NB] = m;
    __syncthreads();
    for (int i = tid; i < m; i += 256) {
        int d = dst[e0 + i];
        int s = src[e0 + i];
        int b = d / nb_sz;
        int p = atomicAdd(&cur[b], 1);
        stage[p] = ((unsigned)s << 8) | (unsigned)(d - b * nb_sz);
    }
    __syncthreads();
    for (int k = tid; k < NB; k += 256) {
        int cnt = ofs[k + 1] - ofs[k];
        rbase[k] = cnt > 0 ? atomicAdd(&gcur[k], cnt) : 0;
    }
    __syncthreads();
    for (int i = tid; i < m; i += 256) {
        int lo = 0, hi = NB;
        while (hi - lo > 1) {
            int mid = (lo + hi) >> 1;
            if (ofs[mid] <= i) lo = mid; else hi = mid;
        }
        pairs[rbase[lo] + (i - ofs[lo])] = stage[i];
    }
}

// per-bucket counting sort -> csr (src only) + ptr (per-node END offsets)
__global__ __launch_bounds__(256) void k_csr_local(const unsigned int* __restrict__ pairs,
                                                   const int* __restrict__ gbase,
                                                   int* __restrict__ csr,
                                                   int* __restrict__ ptr,
                                                   int N, int nb_sz) {
    int b = blockIdx.x;
    int n0 = b * nb_sz;
    if (n0 >= N) return;
    int n1 = n0 + nb_sz; if (n1 > N) n1 = N;
    int nn = n1 - n0;

    __shared__ int cnt[256], scn[256], cur[256];
    int tid = threadIdx.x;
    cnt[tid] = 0;
    __syncthreads();
    int s = gbase[b], e = gbase[b + 1];
    for (int i = s + tid; i < e; i += 256)
        atomicAdd(&cnt[pairs[i] & 0xFFu], 1);
    __syncthreads();
    int c = cnt[tid];
    scn[tid] = c;
    __syncthreads();
    for (int off = 1; off < 256; off <<= 1) {
        int mine = scn[tid];
        int add = (tid >= off) ? scn[tid - off] : 0;
        __syncthreads();
        scn[tid] = mine + add;
        __syncthreads();
    }
    cur[tid] = scn[tid] - c;                      // exclusive prefix
    if (tid < nn) ptr[n0 + tid] = s + scn[tid];   // end offset
    __syncthreads();
    for (int i = s + tid; i < e; i += 256) {
        unsigned int p = pairs[i];
        int pos = atomicAdd(&cur[p & 0xFFu], 1);
        csr[s + pos] = (int)(p >> 8);
    }
}

// ---------------- final gather (2 f32 feats) + bias -> d_out ----------------

__global__ void k_gather2_out(const float* __restrict__ t3,
                              const int* __restrict__ csr,
                              const int* __restrict__ ptr,
                              const float* __restrict__ b3,
                              float* __restrict__ out, int n) {
    int node = blockIdx.x * blockDim.x + threadIdx.x;
    if (node >= n) return;
    int start = node ? ptr[node - 1] : 0;
    int end = ptr[node];
    float a0 = 0.f, a1 = 0.f;
    int j = start;
    for (; j + 1 < end; j += 2) {
        int s0 = csr[j], s1 = csr[j + 1];
        float2 v0 = *reinterpret_cast<const float2*>(t3 + (long long)s0 * 2);
        float2 v1 = *reinterpret_cast<const float2*>(t3 + (long long)s1 * 2);
        a0 += v0.x + v1.x;
        a1 += v0.y + v1.y;
    }
    if (j < end) {
        float2 v = *reinterpret_cast<const float2*>(t3 + (long long)csr[j] * 2);
        a0 += v.x; a1 += v.y;
    }
    float2* o = reinterpret_cast<float2*>(out + (long long)node * 2);
    *o = make_float2(a0 + b3[0], a1 + b3[1]);
}

// ---------------- graph embedding + prediction ----------------

__global__ void k_bounds(const int* __restrict__ gids, int n, int* __restrict__ start) {
    int g = threadIdx.x;
    if (g > N_GRAPHS) return;
    int lo = 0, hi = n;
    while (lo < hi) {
        int mid = (lo + hi) >> 1;
        if (gids[mid] < g) lo = mid + 1; else hi = mid;
    }
    start[g] = lo;
}

__global__ __launch_bounds__(256) void k_gsum2(const float* __restrict__ nf,
                                               const int* __restrict__ gids,
                                               const int* __restrict__ gstart,
                                               float* __restrict__ ge, int N) {
    int c0 = blockIdx.x * GCH;
    if (c0 >= N) return;
    int c1 = c0 + GCH; if (c1 > N) c1 = N;
    int tid = threadIdx.x;
    int ng = tid >> 4;    // node group 0..15
    int f4 = tid & 15;    // float4 column

    int gfirst = gids[c0];
    int glast  = gids[c1 - 1];

    __shared__ float4 red[256];
    for (int g = gfirst; g <= glast; g++) {
        int s = gstart[g];     if (s < c0) s = c0;
        int e = gstart[g + 1]; if (e > c1) e = c1;
        float4 acc = make_float4(0.f, 0.f, 0.f, 0.f);
        for (int i = s + ng; i < e; i += 16) {
            float4 v = *reinterpret_cast<const float4*>(nf + (long long)i * IN_FEATS + f4 * 4);
            acc.x += v.x; acc.y += v.y; acc.z += v.z; acc.w += v.w;
        }
        red[tid] = acc;
        __syncthreads();
        for (int off = 8; off > 0; off >>= 1) {
            if (ng < off) {
                float4 o = red[(ng + off) * 16 + f4];
                float4 m = red[tid];
                m.x += o.x; m.y += o.y; m.z += o.z; m.w += o.w;
                red[tid] = m;
            }
            __syncthreads();
        }
        if (ng == 0 && e > s) {
            float4 m = red[f4];
            atomicAdd(&ge[g * IN_FEATS + f4 * 4 + 0], m.x);
            atomicAdd(&ge[g * IN_FEATS + f4 * 4 + 1], m.y);
            atomicAdd(&ge[g * IN_FEATS + f4 * 4 + 2], m.z);
            atomicAdd(&ge[g * IN_FEATS + f4 * 4 + 3], m.w);
        }
        __syncthreads();
    }
}

__global__ void k_pred(const float* __restrict__ ge,
                       const int* __restrict__ gstart,
                       const float* __restrict__ Wl,
                       const float* __restrict__ bl,
                       float* __restrict__ out) {
    int g = threadIdx.x;
    if (g >= N_GRAPHS) return;
    float cnt = (float)(gstart[g + 1] - gstart[g]);
    float inv = 1.f / fmaxf(cnt, 1.0f);
    float acc = 0.f;
    for (int k = 0; k < IN_FEATS; k++)
        acc += ge[g * IN_FEATS + k] * Wl[k];
    acc = acc * inv + bl[0];
    out[g] = 1.f / (1.f + expf(-acc));
}

extern "C" void kernel_launch(void* const* d_in, const int* in_sizes, int n_in,
                              void* d_out, int out_size, void* d_ws, size_t ws_size,
                              hipStream_t stream) {
    const float* nf = (const float*)d_in[0];   // node_feats f32 [N,64]
    const float* W1 = (const float*)d_in[2];   // [64,32]
    const float* b1 = (const float*)d_in[3];   // [32]
    const float* W2 = (const float*)d_in[4];   // [32,32]
    const float* b2 = (const float*)d_in[5];   // [32]
    const float* W3 = (const float*)d_in[6];   // [32,2]
    const float* b3 = (const float*)d_in[7];   // [2]
    const float* Wl = (const float*)d_in[8];   // [64,1]
    const float* bl = (const float*)d_in[9];   // [1]
    const int* src  = (const int*)d_in[10];
    const int* dst  = (const int*)d_in[11];
    const int* gids = (const int*)d_in[12];

    const int N = in_sizes[0] / IN_FEATS;     // 100000
    const int E = in_sizes[10];               // 1600000
    const int nb_sz = (N + NB - 1) / NB;      // 196 (<=256 required for packing)

    float* out = (float*)d_out;

    // workspace layout:
    unsigned int* tA = (unsigned int*)d_ws;                // bf16 table A [N,32] (6.4MB)
    unsigned int* tB = tA + (size_t)N * 16;                // bf16 table B [N,32] (6.4MB)
    float* t3    = (float*)(tB + (size_t)N * 16);          // [N,2] f32 (0.8MB)
    unsigned int* pairs = (unsigned int*)(t3 + (size_t)N * OUT_DIM); // [E] packed (6.4MB)
    int* csr     = (int*)(pairs + E);                      // [E] (6.4MB)
    int* ptr     = csr + E;                                // [N]
    int* gcount  = ptr + N;                                // [NB]
    int* gbase   = gcount + NB;                            // [NB+1]
    int* gcur    = gbase + NB + 1;                         // [NB]
    float* ge    = (float*)(gcur + NB);                    // [64,64]
    int* gstart  = (int*)(ge + N_GRAPHS * IN_FEATS);       // [65]

    const int TB = 256;
    int nodeBlocks = (N + TB - 1) / TB;
    int partBlocks = (E + PCH - 1) / PCH;
    int fusedBlocks = (N + 15) / 16;
    int gsumBlocks = (N + GCH - 1) / GCH;

    // ---- graph embedding (independent of GCN chain) ----
    hipMemsetAsync(ge, 0, N_GRAPHS * IN_FEATS * sizeof(float), stream);
    k_bounds<<<1, 128, 0, stream>>>(gids, N, gstart);
    k_gsum2<<<gsumBlocks, TB, 0, stream>>>(nf, gids, gstart, ge, N);
    k_pred<<<1, 64, 0, stream>>>(ge, gstart, Wl, bl, out);

    // ---- CSR build (once, reused for all 3 layers) ----
    hipMemsetAsync(gcount, 0, NB * sizeof(int), stream);
    k_hist<<<256, TB, 0, stream>>>(dst, gcount, E, nb_sz);
    k_scan512<<<1, TB, 0, stream>>>(gcount, gbase, gcur, E);
    k_partition<<<partBlocks, TB, 0, stream>>>(src, dst, gcur, pairs, E, nb_sz);
    k_csr_local<<<NB, TB, 0, stream>>>(pairs, gbase, csr, ptr, N, nb_sz);

    // ---- GCN chain (fused gather+linear at layer boundaries) ----
    k_lin1<<<nodeBlocks, TB, 0, stream>>>(nf, W1, tA, N);
    k_gather_lin2<<<fusedBlocks, TB, 0, stream>>>(tA, csr, ptr, b1, W2, tB, N);
    k_gather_lin3<<<fusedBlocks, TB, 0, stream>>>(tB, csr, ptr, b2, W3, t3, N);
    k_gather2_out<<<nodeBlocks, TB, 0, stream>>>(t3, csr, ptr, b3, out + N_GRAPHS, N);
}